// Round 5
// baseline (630.787 us; speedup 1.0000x reference)
//
#include <hip/hip_runtime.h>
#include <cstddef>

#define EPSV 1e-5f

typedef __attribute__((ext_vector_type(8))) short frag8;   // 8 bf16 (4 VGPRs)
typedef __attribute__((ext_vector_type(4))) float f32x4;   // MFMA acc

__device__ __forceinline__ float lrelu01(float v) { return v > 0.f ? v : 0.01f * v; }
__device__ __forceinline__ void atomAddF(float* p, float v) { unsafeAtomicAdd(p, v); }
__device__ __forceinline__ unsigned fkey(float f) {
    unsigned u = __float_as_uint(f);
    return (u & 0x80000000u) ? ~u : (u | 0x80000000u);
}
__device__ __forceinline__ unsigned short f2b(float f) {  // RNE float->bf16
    unsigned u = __float_as_uint(f);
    unsigned r = u + 0x7fffu + ((u >> 16) & 1u);
    return (unsigned short)(r >> 16);
}
__device__ __forceinline__ float b2f(unsigned short h) {
    return __uint_as_float(((unsigned)h) << 16);
}
__device__ __forceinline__ float blo(unsigned u) { return __uint_as_float(u << 16); }
__device__ __forceinline__ float bhi(unsigned u) { return __uint_as_float(u & 0xffff0000u); }

static inline unsigned cdivu(unsigned a, unsigned b) { return (a + b - 1) / b; }

// device-scope spin barrier for a small, fully-co-resident grid.
// cnt lives in memset-zeroed workspace; replay-after-completion is idempotent.
__device__ __forceinline__ void gbar(unsigned* cnt, unsigned target) {
    __syncthreads();
    if (threadIdx.x == 0) {
        __threadfence();
        atomicAdd(cnt, 1u);
        while (atomicAdd(cnt, 0u) < target) { }
        __threadfence();
    }
    __syncthreads();
}

// ================= graph prep bodies =================

__device__ void degrank_body(int bid, const int* __restrict__ dst, int* __restrict__ deg,
                             int* __restrict__ rank, int E) {
    int e = bid * 256 + threadIdx.x;
    if (e < E) rank[e] = atomicAdd(&deg[dst[e]], 1);
}

__device__ void scan_local_body(int bid, const int* __restrict__ deg, int* __restrict__ startv,
                                int* __restrict__ bsum, float* __restrict__ dinv, int n) {
    __shared__ int t0[256];
    int tid = threadIdx.x;
    int i = bid * 256 + tid;
    int v = (i < n) ? deg[i] : 0;
    if (i < n) dinv[i] = rsqrtf((float)(v + 1));  // +1 self loop
    t0[tid] = v;
    __syncthreads();
    for (int o = 1; o < 256; o <<= 1) {
        int add = (tid >= o) ? t0[tid - o] : 0;
        __syncthreads();
        t0[tid] += add;
        __syncthreads();
    }
    if (i < n) startv[i] = t0[tid] - v;
    if (tid == 255) bsum[bid] = t0[255];
}

// 256-thread scan over up to 512 block sums (ping-pong Hillis-Steele)
__device__ void scan_bsum_body(int* __restrict__ bsum, int nb) {
    __shared__ int t0[512];
    __shared__ int t1[512];
    int tid = threadIdx.x;
    int v0 = (tid < nb) ? bsum[tid] : 0;
    int v1 = (tid + 256 < nb) ? bsum[tid + 256] : 0;
    t0[tid] = v0; t0[tid + 256] = v1;
    __syncthreads();
    int* a = t0; int* b = t1;
    for (int o = 1; o < 512; o <<= 1) {
        b[tid]       = a[tid]       + ((tid >= o)       ? a[tid - o]       : 0);
        b[tid + 256] = a[tid + 256] + ((tid + 256 >= o) ? a[tid + 256 - o] : 0);
        __syncthreads();
        int* t = a; a = b; b = t;
    }
    if (tid < nb) bsum[tid] = a[tid] - v0;
    if (tid + 256 < nb) bsum[tid + 256] = a[tid + 256] - v1;
}

// fill using local startv + block-prefix bsum (no scan_add pass needed)
__device__ void fill_body(int bid, const int* __restrict__ src, const int* __restrict__ dst,
                          const int* __restrict__ rank, const int* __restrict__ startv,
                          const int* __restrict__ bsum, int* __restrict__ csr, int E) {
    int e = bid * 256 + threadIdx.x;
    if (e < E) {
        int d = dst[e];
        csr[startv[d] + bsum[d >> 8] + rank[e]] = src[e];
    }
}

// ================= small bodies =================

__device__ void wconv_body(int bid, const float* __restrict__ s0, const float* __restrict__ s1,
                           const float* __restrict__ s2, const float* __restrict__ s3,
                           const float* __restrict__ s4, const float* __restrict__ s5,
                           const float* __restrict__ s6, const float* __restrict__ s7,
                           unsigned short* __restrict__ dst) {
    int t = bid * 256 + threadIdx.x;
    if (t >= 278528) return;
    const float* srcs[8] = {s0, s1, s2, s3, s4, s5, s6, s7};
    const int off[9] = {0, 8192, 139264, 143360, 147456, 163840, 180224, 196608, 278528};
    int seg = 0;
    while (t >= off[seg + 1]) ++seg;
    unsigned short v = f2b(srcs[seg][t - off[seg]]);
    if (seg == 1) {
        int li = t - 8192;
        int rch = li >> 7, k = li & 127;
        int cb = rch >> 7, r = rch & 127;
        int flat = ((r >> 4) * 4 + (k >> 5)) * 64 + ((k >> 3) & 3) * 16 + (r & 15);
        dst[8192 + cb * 16384 + flat * 8 + (k & 7)] = v;
    } else {
        dst[t] = v;
    }
}

__device__ void h1_body(int bid, const float* __restrict__ x, const float* __restrict__ w,
                        const float* __restrict__ b, unsigned short* __restrict__ h1, int n) {
    int node = bid * 256 + threadIdx.x;
    if (node >= n) return;
    float x0 = x[node * 3], x1 = x[node * 3 + 1], x2 = x[node * 3 + 2];
    unsigned short* o = h1 + (size_t)node * 64;
#pragma unroll
    for (int cp = 0; cp < 8; ++cp) {
        unsigned short tmp[8];
#pragma unroll
        for (int t = 0; t < 8; ++t) {
            int c = cp * 8 + t;
            float v = x0 * w[c * 3] + x1 * w[c * 3 + 1] + x2 * w[c * 3 + 2] + b[c];
            tmp[t] = f2b(fmaxf(v, 0.f));
        }
        *(float4*)(o + cp * 8) = *(float4*)tmp;
    }
}

__device__ void prebn_body(int bid, const float* __restrict__ z, const float* __restrict__ sum2,
                           const float* __restrict__ ss2, unsigned short* __restrict__ a3f,
                           int n16, float invn) {
    int t = bid * 256 + threadIdx.x;
    if (t >= n16) return;
    int row = t >> 4, cp = t & 15;
    int c = cp * 8;
    const float* src = z + (size_t)row * 128 + c;
    float4 v0 = *(const float4*)src;
    float4 v1 = *(const float4*)(src + 4);
    float vv[8] = {v0.x, v0.y, v0.z, v0.w, v1.x, v1.y, v1.z, v1.w};
    unsigned short o[8];
#pragma unroll
    for (int i = 0; i < 8; ++i) {
        float m = sum2[c + i] * invn;
        float var = ss2[c + i] * invn - m * m;
        o[i] = f2b(fmaxf((vv[i] - m) * rsqrtf(var + EPSV), 0.f));
    }
    int tile = row >> 7, r = row & 127;
    int flat = ((r >> 4) * 4 + (cp >> 2)) * 64 + (cp & 3) * 16 + (r & 15);
    *(float4*)(a3f + (size_t)tile * 16384 + flat * 8) = *(float4*)o;
}

// ================= MFMA GEMM body (generic, BK=32) =================
enum { MF_BIAS = 1, MF_LRELU = 2, MF_DINV = 4, MF_STOREF = 8, MF_STOREB = 16,
       MF_STATS = 32, MF_COLSUM = 64 };

template <int BN, int MODE>
__device__ void mgemm_body(int bx, int by,
                           const unsigned short* __restrict__ A, int lda, int K,
                           const unsigned short* __restrict__ W,  // [C][K]
                           const float* __restrict__ bias,
                           float* __restrict__ OutF, unsigned short* __restrict__ OutB, int ldo,
                           const float* __restrict__ dinv,
                           float* __restrict__ sum_o, float* __restrict__ ss_o,
                           unsigned* __restrict__ maxk_o) {
    constexpr int BM = 128;
    constexpr int LDT = 40;
    __shared__ unsigned short As[BM * LDT];
    __shared__ unsigned short Ws[BN * LDT];
    __shared__ float redS[2 * 128];
    __shared__ unsigned redM[128];

    const int tid = threadIdx.x;
    const int wid = tid >> 6, lane = tid & 63;
    const int quad = lane >> 4, lrow = lane & 15;
    const int bn0 = bx * BM;
    const int bc0 = by * BN;

    constexpr int NI = (BN == 128) ? 4 : 2;
    constexpr int NJ = 4;
    const int wm = (BN == 128) ? (wid & 1) * 64 : wid * 32;
    const int wn = (BN == 128) ? (wid >> 1) * 64 : 0;

    if (MODE & (MF_STATS | MF_COLSUM)) {
        for (int c = tid; c < BN; c += 256) {
            redS[c] = 0.f; redS[128 + c] = 0.f; redM[c] = 0u;
        }
    }

    f32x4 acc[NI][NJ] = {};

    for (int k0 = 0; k0 < K; k0 += 32) {
#pragma unroll
        for (int h = 0; h < 2; ++h) {
            int ch = tid + h * 256;
            int row = ch >> 2, cp = ch & 3;
            const unsigned short* src = A + (size_t)(bn0 + row) * lda + k0 + cp * 8;
            *(float4*)&As[row * LDT + cp * 8] = *(const float4*)src;
        }
#pragma unroll
        for (int h = 0; h < BN / 64; ++h) {
            int ch = tid + h * 256;
            int row = ch >> 2, cp = ch & 3;
            const unsigned short* src = W + (size_t)(bc0 + row) * K + k0 + cp * 8;
            *(float4*)&Ws[row * LDT + cp * 8] = *(const float4*)src;
        }
        __syncthreads();
        frag8 af[NI], bf[NJ];
#pragma unroll
        for (int i = 0; i < NI; ++i)
            af[i] = *(const frag8*)&As[(wm + i * 16 + lrow) * LDT + quad * 8];
#pragma unroll
        for (int j = 0; j < NJ; ++j)
            bf[j] = *(const frag8*)&Ws[(wn + j * 16 + lrow) * LDT + quad * 8];
#pragma unroll
        for (int i = 0; i < NI; ++i)
#pragma unroll
            for (int j = 0; j < NJ; ++j)
                acc[i][j] = __builtin_amdgcn_mfma_f32_16x16x32_bf16(af[i], bf[j], acc[i][j], 0, 0, 0);
        __syncthreads();
    }

#pragma unroll
    for (int j = 0; j < NJ; ++j) {
        const int col = bc0 + wn + j * 16 + lrow;
        float bv = (MODE & MF_BIAS) ? bias[col] : 0.f;
        float s = 0.f, q = 0.f, m = -3.4e38f;
#pragma unroll
        for (int i = 0; i < NI; ++i) {
            const int rowb = bn0 + wm + i * 16 + quad * 4;
#pragma unroll
            for (int r = 0; r < 4; ++r) {
                float t = acc[i][j][r] + bv;
                if (MODE & MF_LRELU) t = lrelu01(t);
                if (MODE & MF_DINV) t *= dinv[rowb + r];
                if (MODE & MF_STOREF) OutF[(size_t)(rowb + r) * ldo + col] = t;
                if (MODE & MF_STOREB) OutB[(size_t)(rowb + r) * ldo + col] = f2b(t);
                s += t; q += t * t; m = fmaxf(m, t);
            }
        }
        if (MODE & (MF_STATS | MF_COLSUM)) {
            s += __shfl_xor(s, 16); s += __shfl_xor(s, 32);
            if (MODE & MF_STATS) {
                q += __shfl_xor(q, 16); q += __shfl_xor(q, 32);
                m = fmaxf(m, __shfl_xor(m, 16)); m = fmaxf(m, __shfl_xor(m, 32));
            }
            if (quad == 0) {
                int lc = wn + j * 16 + lrow;
                atomicAdd(&redS[lc], s);
                if (MODE & MF_STATS) {
                    atomicAdd(&redS[128 + lc], q);
                    atomicMax(&redM[lc], fkey(m));
                }
            }
        }
    }
    if (MODE & (MF_STATS | MF_COLSUM)) {
        __syncthreads();
        for (int c = tid; c < BN; c += 256) {
            atomAddF(&sum_o[bc0 + c], redS[c]);
            if (MODE & MF_STATS) {
                atomAddF(&ss_o[bc0 + c], redS[128 + c]);
                atomicMax(&maxk_o[bc0 + c], redM[c]);
            }
        }
    }
}

// standalone GEMM wrapper; SWAP=1 maps row-tile to blockIdx.y so the two
// column-blocks of one row-tile are dispatch-adjacent (A tile L2-hit).
template <int BN, int MODE, int SWAP>
__launch_bounds__(256)
__global__ void k_mgemm(const unsigned short* __restrict__ A, int lda, int K,
                        const unsigned short* __restrict__ W,
                        const float* __restrict__ bias,
                        float* __restrict__ OutF, unsigned short* __restrict__ OutB, int ldo,
                        const float* __restrict__ dinv,
                        float* __restrict__ sum_o, float* __restrict__ ss_o,
                        unsigned* __restrict__ maxk_o) {
    int bx = SWAP ? blockIdx.y : blockIdx.x;
    int by = SWAP ? blockIdx.x : blockIdx.y;
    mgemm_body<BN, MODE>(bx, by, A, lda, K, W, bias, OutF, OutB, ldo, dinv, sum_o, ss_o, maxk_o);
}

// ================= z3 stats GEMM: no LDS, no barrier =================
// tile = bid>>3: 8 consecutive blocks share one 32KB A tile (L2 reuse).
__device__ void z3_body(int bid,
                        const unsigned short* __restrict__ AF,
                        const unsigned short* __restrict__ WF,
                        const float* __restrict__ bias,
                        float* __restrict__ sum_o, float* __restrict__ ss_o,
                        unsigned* __restrict__ maxk_o) {
    const int tid = threadIdx.x;
    const int wid = tid >> 6, lane = tid & 63;
    const int quad = lane >> 4, lrow = lane & 15;

    const int tile = bid >> 3;
    const int cb = bid & 7;
    const unsigned short* At = AF + (size_t)tile * 16384;
    const unsigned short* Wt = WF + (size_t)cb * 16384;

    const int ar = (wid & 1) * 4;
    const int wc = (wid >> 1) * 4;
    f32x4 acc[4][4] = {};
#pragma unroll
    for (int kc = 0; kc < 4; ++kc) {
        frag8 af[4], bf[4];
#pragma unroll
        for (int i = 0; i < 4; ++i)
            af[i] = *(const frag8*)&At[(((ar + i) * 4 + kc) * 64 + lane) * 8];
#pragma unroll
        for (int j = 0; j < 4; ++j)
            bf[j] = *(const frag8*)&Wt[(((wc + j) * 4 + kc) * 64 + lane) * 8];
#pragma unroll
        for (int i = 0; i < 4; ++i)
#pragma unroll
            for (int j = 0; j < 4; ++j)
                acc[i][j] = __builtin_amdgcn_mfma_f32_16x16x32_bf16(af[i], bf[j], acc[i][j], 0, 0, 0);
    }

#pragma unroll
    for (int j = 0; j < 4; ++j) {
        int c = cb * 128 + (wc + j) * 16 + lrow;
        float bv = bias[c];
        float s = 0.f, q = 0.f, m = -3.4e38f;
#pragma unroll
        for (int i = 0; i < 4; ++i)
#pragma unroll
            for (int r = 0; r < 4; ++r) {
                float t = acc[i][j][r] + bv;
                s += t; q += t * t; m = fmaxf(m, t);
            }
        s += __shfl_xor(s, 16); s += __shfl_xor(s, 32);
        q += __shfl_xor(q, 16); q += __shfl_xor(q, 32);
        m = fmaxf(m, __shfl_xor(m, 16)); m = fmaxf(m, __shfl_xor(m, 32));
        if (quad == 0) {
            atomAddF(&sum_o[c], s);
            atomAddF(&ss_o[c], q);
            atomicMax(&maxk_o[c], fkey(m));
        }
    }
}

// ================= fat kernels =================

__launch_bounds__(256)
__global__ void FK1(const int* __restrict__ dst, int* __restrict__ deg, int* __restrict__ rank,
                    int E, int EB,
                    const float* s0, const float* s1, const float* s2, const float* s3,
                    const float* s4, const float* s5, const float* s6, const float* s7,
                    unsigned short* __restrict__ WB, int WCB,
                    const float* __restrict__ x, const float* __restrict__ c1w,
                    const float* __restrict__ c1b, unsigned short* __restrict__ B1, int n) {
    int b = blockIdx.x;
    if (b < EB) { degrank_body(b, dst, deg, rank, E); return; }
    b -= EB;
    if (b < WCB) { wconv_body(b, s0, s1, s2, s3, s4, s5, s6, s7, WB); return; }
    b -= WCB;
    h1_body(b, x, c1w, c1b, B1, n);
}

__launch_bounds__(256)
__global__ void FK2(const unsigned short* __restrict__ A, int lda, int K,
                    const unsigned short* __restrict__ W, const float* __restrict__ bias,
                    float* __restrict__ OutF, int ldo,
                    float* __restrict__ sum_o, float* __restrict__ ss_o,
                    unsigned* __restrict__ maxk_o, int GXz,
                    const int* __restrict__ deg, int* __restrict__ startv,
                    int* __restrict__ bsum, float* __restrict__ dinvv, int n) {
    if ((int)blockIdx.x < GXz)
        mgemm_body<128, (MF_BIAS | MF_STOREF | MF_STATS)>(
            blockIdx.x, 0, A, lda, K, W, bias, OutF, nullptr, ldo, nullptr, sum_o, ss_o, maxk_o);
    else
        scan_local_body(blockIdx.x - GXz, deg, startv, bsum, dinvv, n);
}

__launch_bounds__(256)
__global__ void FK3(const float* __restrict__ z, const float* __restrict__ sum2,
                    const float* __restrict__ ss2, unsigned short* __restrict__ a3f,
                    int n16, float invn, int PB, int* __restrict__ bsum, int nb) {
    if ((int)blockIdx.x < PB) prebn_body(blockIdx.x, z, sum2, ss2, a3f, n16, invn);
    else scan_bsum_body(bsum, nb);
}

// FK4: z3 stats GEMM ||| CSR fill, INTERLEAVED block mapping (even->z3, odd->fill)
// so both workloads run concurrently: fill's scatter latency hides under z3's
// MFMA+stream. (Round-3 lesson: appended mapping serializes, in-order dispatch.)
__launch_bounds__(256)
__global__ void FK4(const unsigned short* __restrict__ AF, const unsigned short* __restrict__ WF,
                    const float* __restrict__ bias,
                    float* __restrict__ sum_o, float* __restrict__ ss_o,
                    unsigned* __restrict__ maxk_o, int NZ, int EB,
                    const int* __restrict__ src, const int* __restrict__ dst,
                    const int* __restrict__ rank, const int* __restrict__ startv,
                    const int* __restrict__ bsum, int* __restrict__ csr, int E) {
    int b = blockIdx.x;
    int mn = (NZ < EB) ? NZ : EB;
    if (b < 2 * mn) {
        if ((b & 1) == 0) z3_body(b >> 1, AF, WF, bias, sum_o, ss_o, maxk_o);
        else fill_body(b >> 1, src, dst, rank, startv, bsum, csr, E);
    } else if (NZ > EB) {
        z3_body(b - EB, AF, WF, bias, sum_o, ss_o, maxk_o);
    } else {
        fill_body(b - NZ, src, dst, rank, startv, bsum, csr, E);
    }
}

// k_tnet: fc1 + fc2 + fc3 in ONE 32-block kernel with device spin barriers.
// 32 blocks trivially co-resident; counters zeroed by the per-iteration memset.
__launch_bounds__(256)
__global__ void k_tnet(const float* __restrict__ sum3, const float* __restrict__ ss3,
                       const unsigned* __restrict__ maxk,
                       const float* __restrict__ f1w, const float* __restrict__ f1b,
                       const float* __restrict__ f2w, const float* __restrict__ f2bias,
                       const float* __restrict__ f3w, const float* __restrict__ f3b,
                       float* __restrict__ a1, float* __restrict__ a2,
                       float* __restrict__ T9,
                       unsigned* __restrict__ cnt1, unsigned* __restrict__ cnt2, float invn) {
    __shared__ float g[1024];
    __shared__ float a1s[512];
    int tid = threadIdx.x;
    int bid = blockIdx.x;
    // ---- g = relu(bn(maxpool)) ----
    for (int c = tid; c < 1024; c += 256) {
        float m = sum3[c] * invn;
        float var = ss3[c] * invn - m * m;
        unsigned k = maxk[c];
        unsigned u = (k & 0x80000000u) ? (k & 0x7FFFFFFFu) : ~k;
        g[c] = fmaxf((__uint_as_float(u) - m) * rsqrtf(var + EPSV), 0.f);
    }
    __syncthreads();
    // ---- fc1: 16 rows/block, 16 lanes/row ----
    {
        int row = bid * 16 + (tid >> 4);
        int part = tid & 15;
        const float* w = f1w + (size_t)row * 1024 + part * 64;
        const float* gg = g + part * 64;
        float s = 0.f;
#pragma unroll 4
        for (int k = 0; k < 64; k += 4) {
            float4 wv = *(const float4*)(w + k);
            s = fmaf(wv.x, gg[k], s);
            s = fmaf(wv.y, gg[k + 1], s);
            s = fmaf(wv.z, gg[k + 2], s);
            s = fmaf(wv.w, gg[k + 3], s);
        }
        s += __shfl_xor(s, 1); s += __shfl_xor(s, 2);
        s += __shfl_xor(s, 4); s += __shfl_xor(s, 8);
        if (part == 0) a1[row] = fmaxf(s + f1b[row], 0.f);
    }
    gbar(cnt1, 32);
    // ---- fc2: 8 rows/block, 32 lanes/row ----
    a1s[tid] = a1[tid];
    a1s[tid + 256] = a1[tid + 256];
    __syncthreads();
    {
        int row = bid * 8 + (tid >> 5);
        int part = tid & 31;
        const float* w = f2w + (size_t)row * 512 + part * 16;
        const float* aa = a1s + part * 16;
        float s = 0.f;
#pragma unroll
        for (int k = 0; k < 16; k += 4) {
            float4 wv = *(const float4*)(w + k);
            s = fmaf(wv.x, aa[k], s);
            s = fmaf(wv.y, aa[k + 1], s);
            s = fmaf(wv.z, aa[k + 2], s);
            s = fmaf(wv.w, aa[k + 3], s);
        }
        s += __shfl_xor(s, 1); s += __shfl_xor(s, 2); s += __shfl_xor(s, 4);
        s += __shfl_xor(s, 8); s += __shfl_xor(s, 16);
        if (part == 0) a2[row] = fmaxf(s + f2bias[row], 0.f);
    }
    gbar(cnt2, 32);
    // ---- fc3 (block 0): 9 rows, 16 lanes/row ----
    if (bid == 0 && tid < 144) {
        int r = tid >> 4, kk = (tid & 15) * 16;
        const float* wr = f3w + r * 256 + kk;
        float s = 0.f;
#pragma unroll
        for (int k = 0; k < 16; ++k) s = fmaf(wr[k], a2[kk + k], s);
        s += __shfl_xor(s, 1); s += __shfl_xor(s, 2);
        s += __shfl_xor(s, 4); s += __shfl_xor(s, 8);
        if ((tid & 15) == 0) {
            s += f3b[r];
            if (r == 0 || r == 4 || r == 8) s += 1.f;
            T9[r] = s;
        }
    }
}

// ================= fused gather + LN =================
// nd = dummy row index (points at the shared 256B zero row at B2 + N*128 entries:
// nd = 2N when q rows are 64ch, nd = N when 128ch).
template <int CH>
__launch_bounds__(256)
__global__ void k_gln(const int* __restrict__ startv, const int* __restrict__ bsum,
                      const int* __restrict__ degv,
                      const int* __restrict__ csr, const unsigned short* __restrict__ q,
                      const unsigned short* __restrict__ nf, const float* __restrict__ dinv,
                      const float* __restrict__ gcn_b, const float* __restrict__ lng,
                      const float* __restrict__ lnb, unsigned short* __restrict__ outp,
                      int ldo, int n, int nd) {
    constexpr int GRP = (CH == 64) ? 8 : 4;   // rows in flight per load instr
    constexpr int PL  = 64 / GRP;             // lanes per row slice
    constexpr int TT  = 16 / GRP;             // load instrs per 16-edge chunk
    constexpr int CPL = CH / PL;              // = 8 channels per lane
    const int wv = threadIdx.x >> 6, lane = threadIdx.x & 63;
    const int g = lane / PL, p = lane & (PL - 1);
    int node = blockIdx.x * 4 + wv;
    if (node >= n) return;

    const unsigned short* qp = q + (size_t)p * CPL;

    float acc[CPL];
    {
        uint4 v = *(const uint4*)(qp + (size_t)node * CH);
        unsigned sv[4] = {v.x, v.y, v.z, v.w};
        if (g == 0) {
#pragma unroll
            for (int d = 0; d < 4; ++d) { acc[2 * d] = blo(sv[d]); acc[2 * d + 1] = bhi(sv[d]); }
        } else {
#pragma unroll
            for (int k = 0; k < CPL; ++k) acc[k] = 0.f;
        }
    }

    int s0 = startv[node] + bsum[node >> 8], cnt = degv[node];
    const int* cs = csr + s0;
    int sidx[TT];
#pragma unroll
    for (int t = 0; t < TT; ++t) { int j = t * GRP + g; sidx[t] = (j < cnt) ? cs[j] : nd; }
    for (int j0 = 0; j0 < cnt; j0 += 16) {
        uint4 buf[TT];
#pragma unroll
        for (int t = 0; t < TT; ++t)
            buf[t] = *(const uint4*)(qp + (size_t)(unsigned)sidx[t] * CH);
#pragma unroll
        for (int t = 0; t < TT; ++t) {
            int j = j0 + 16 + t * GRP + g;
            sidx[t] = (j < cnt) ? cs[j] : nd;
        }
#pragma unroll
        for (int t = 0; t < TT; ++t) {
            unsigned bw[4] = {buf[t].x, buf[t].y, buf[t].z, buf[t].w};
#pragma unroll
            for (int d = 0; d < 4; ++d) {
                acc[2 * d] += blo(bw[d]);
                acc[2 * d + 1] += bhi(bw[d]);
            }
        }
    }

#pragma unroll
    for (int k = 0; k < CPL; ++k) {
#pragma unroll
        for (int off = PL; off < 64; off <<= 1) acc[k] += __shfl_xor(acc[k], off);
    }

    float di = dinv[node];
    float nv[CPL], bv[CPL];
    {
        uint4 v = *(const uint4*)(nf + (size_t)node * CH + p * CPL);
        unsigned sv[4] = {v.x, v.y, v.z, v.w};
#pragma unroll
        for (int d = 0; d < 4; ++d) { nv[2 * d] = blo(sv[d]); nv[2 * d + 1] = bhi(sv[d]); }
    }
    const float* gb = gcn_b + p * CPL;
#pragma unroll
    for (int k = 0; k < CPL; ++k) bv[k] = lrelu01(di * acc[k] + gb[k]);

    float s = 0.f, ss = 0.f;
#pragma unroll
    for (int k = 0; k < CPL; ++k) { s += nv[k] + bv[k]; ss += nv[k] * nv[k] + bv[k] * bv[k]; }
#pragma unroll
    for (int off = 32; off > 0; off >>= 1) { s += __shfl_xor(s, off); ss += __shfl_xor(ss, off); }
    const float inv = 1.f / (float)(GRP * 2 * CH);  // GRP-way replication * 2*CH channels
    float mu = s * inv;
    float var = ss * inv - mu * mu;
    float rsg = rsqrtf(var + EPSV);

    unsigned short* orow = outp + (size_t)node * ldo;
    if (g == 0) {
        unsigned short tmp[CPL];
        const float* lg = lng + p * CPL; const float* lb = lnb + p * CPL;
#pragma unroll
        for (int k = 0; k < CPL; ++k) tmp[k] = f2b((nv[k] - mu) * rsg * lg[k] + lb[k]);
        *(uint4*)(orow + p * CPL) = *(uint4*)tmp;
    } else if (g == 1) {
        unsigned short tmp[CPL];
        const float* lg = lng + CH + p * CPL; const float* lb = lnb + CH + p * CPL;
#pragma unroll
        for (int k = 0; k < CPL; ++k) tmp[k] = f2b((bv[k] - mu) * rsg * lg[k] + lb[k]);
        *(uint4*)(orow + CH + p * CPL) = *(uint4*)tmp;
    }
}

// ================= remaining standalone kernels =================

// xg from T9; also emits xdot[node] = xg_row(dot)ow[:,256:320]
__launch_bounds__(256)
__global__ void k_xg2(const float* __restrict__ x, const float* __restrict__ T9,
                      const float* __restrict__ w, const float* __restrict__ b,
                      const float* __restrict__ ow,
                      unsigned short* __restrict__ xg, float* __restrict__ xdot, int n) {
    __shared__ float owS[256];
    __shared__ float T9s[9];
    int tid = threadIdx.x;
    owS[tid] = ow[(tid >> 6) * 320 + 256 + (tid & 63)];
    if (tid < 9) T9s[tid] = T9[tid];
    __syncthreads();
    int node = blockIdx.x * 256 + tid;
    if (node >= n) return;
    float x0 = x[node * 3], x1 = x[node * 3 + 1], x2 = x[node * 3 + 2];
    float h0 = x0 * T9s[0] + x1 * T9s[3] + x2 * T9s[6];
    float h1 = x0 * T9s[1] + x1 * T9s[4] + x2 * T9s[7];
    float h2 = x0 * T9s[2] + x1 * T9s[5] + x2 * T9s[8];
    unsigned short* o = xg + (size_t)node * 320;
    float d0 = 0.f, d1 = 0.f, d2 = 0.f, d3 = 0.f;
#pragma unroll
    for (int cp = 0; cp < 8; ++cp) {
        unsigned short tmp[8];
#pragma unroll
        for (int t = 0; t < 8; ++t) {
            int c = cp * 8 + t;
            float v = lrelu01(h0 * w[c * 3] + h1 * w[c * 3 + 1] + h2 * w[c * 3 + 2] + b[c]);
            tmp[t] = f2b(v);
            d0 = fmaf(v, owS[c], d0);
            d1 = fmaf(v, owS[64 + c], d1);
            d2 = fmaf(v, owS[128 + c], d2);
            d3 = fmaf(v, owS[192 + c], d3);
        }
        *(float4*)(o + cp * 8) = *(float4*)tmp;
    }
    *(float4*)(xdot + (size_t)node * 4) = make_float4(d0, d1, d2, d3);
}

// ---------------- fused li+gc (block 1, BN=64) ----------------
template <int BN>
__launch_bounds__(256)
__global__ void k_ligc(const unsigned short* __restrict__ A, int lda, int K,
                       const unsigned short* __restrict__ Wli, const float* __restrict__ bli,
                       const unsigned short* __restrict__ Wgc, const float* __restrict__ dinv,
                       unsigned short* __restrict__ NF, int ldnf,
                       unsigned short* __restrict__ Q, int ldq) {
    constexpr int BM = 128;
    constexpr int LDT = 40;
    constexpr int LDT2 = BN + 8;
    __shared__ unsigned short SA[BM * LDT2];
    __shared__ unsigned short Ws[BN * LDT];
    __shared__ unsigned short As[BM * LDT];

    const int tid = threadIdx.x;
    const int wid = tid >> 6, lane = tid & 63;
    const int quad = lane >> 4, lrow = lane & 15;
    const int bn0 = blockIdx.x * BM;
    constexpr int NI = (BN == 128) ? 4 : 2;
    constexpr int NJ = 4;
    const int wm = (BN == 128) ? (wid & 1) * 64 : wid * 32;
    const int wn = (BN == 128) ? (wid >> 1) * 64 : 0;

    // ---- stage 1: nf = lrelu(A x Wli^T + bli) -> NF global + SA ----
    {
        f32x4 acc[NI][NJ] = {};
        for (int k0 = 0; k0 < K; k0 += 32) {
#pragma unroll
            for (int h = 0; h < 2; ++h) {
                int ch = tid + h * 256;
                int row = ch >> 2, cp = ch & 3;
                *(float4*)&As[row * LDT + cp * 8] =
                    *(const float4*)(A + (size_t)(bn0 + row) * lda + k0 + cp * 8);
            }
#pragma unroll
            for (int h = 0; h < BN / 64; ++h) {
                int ch = tid + h * 256;
                int row = ch >> 2, cp = ch & 3;
                *(float4*)&Ws[row * LDT + cp * 8] =
                    *(const float4*)(Wli + (size_t)row * K + k0 + cp * 8);
            }
            __syncthreads();
            frag8 af[NI], bf[NJ];
#pragma unroll
            for (int i = 0; i < NI; ++i)
                af[i] = *(const frag8*)&As[(wm + i * 16 + lrow) * LDT + quad * 8];
#pragma unroll
            for (int j = 0; j < NJ; ++j)
                bf[j] = *(const frag8*)&Ws[(wn + j * 16 + lrow) * LDT + quad * 8];
#pragma unroll
            for (int i = 0; i < NI; ++i)
#pragma unroll
                for (int j = 0; j < NJ; ++j)
                    acc[i][j] = __builtin_amdgcn_mfma_f32_16x16x32_bf16(af[i], bf[j], acc[i][j], 0, 0, 0);
            __syncthreads();
        }
#pragma unroll
        for (int j = 0; j < NJ; ++j) {
            const int col = wn + j * 16 + lrow;
            float bv = bli[col];
#pragma unroll
            for (int i = 0; i < NI; ++i) {
                const int rowl = wm + i * 16 + quad * 4;
#pragma unroll
                for (int r = 0; r < 4; ++r) {
                    unsigned short h = f2b(lrelu01(acc[i][j][r] + bv));
                    NF[(size_t)(bn0 + rowl + r) * ldnf + col] = h;
                    SA[(rowl + r) * LDT2 + col] = h;
                }
            }
        }
        __syncthreads();
    }
    // ---- stage 2: q = (nf x Wgc^T) * dinv -> Q ----
    {
        f32x4 acc[NI][NJ] = {};
        for (int k0 = 0; k0 < BN; k0 += 32) {
#pragma unroll
            for (int h = 0; h < BN / 64; ++h) {
                int ch = tid + h * 256;
                int row = ch >> 2, cp = ch & 3;
                *(float4*)&Ws[row * LDT + cp * 8] =
                    *(const float4*)(Wgc + (size_t)row * BN + k0 + cp * 8);
            }
            __syncthreads();
            frag8 af[NI], bf[NJ];
#pragma unroll
            for (int i = 0; i < NI; ++i)
                af[i] = *(const frag8*)&SA[(wm + i * 16 + lrow) * LDT2 + k0 + quad * 8];
#pragma unroll
            for (int j = 0; j < NJ; ++j)
                bf[j] = *(const frag8*)&Ws[(wn + j * 16 + lrow) * LDT + quad * 8];
#pragma unroll
            for (int i = 0; i < NI; ++i)
#pragma unroll
                for (int j = 0; j < NJ; ++j)
                    acc[i][j] = __builtin_amdgcn_mfma_f32_16x16x32_bf16(af[i], bf[j], acc[i][j], 0, 0, 0);
            __syncthreads();
        }
#pragma unroll
        for (int j = 0; j < NJ; ++j) {
            const int col = wn + j * 16 + lrow;
#pragma unroll
            for (int i = 0; i < NI; ++i) {
                const int rowb = bn0 + wm + i * 16 + quad * 4;
#pragma unroll
                for (int r = 0; r < 4; ++r) {
                    float t = acc[i][j][r] * dinv[rowb + r];
                    Q[(size_t)(rowb + r) * ldq + col] = f2b(t);
                }
            }
        }
    }
}

// ---------------- fused conv2 + li2 + gc2 (block 2): 3-stage GEMM chain ----------------
// hmid = lrelu(A x Wcv^T + bcv) lives only in LDS; nf overwrites it in-place.
// A (hln1) and NF share the same buffer: each block fully consumes its global A
// rows in stage 0 before overwriting them (stage 1), and touches only own rows.
__launch_bounds__(256)
__global__ void k_cligc(const unsigned short* __restrict__ A,   // [n,128] hln1
                        const unsigned short* __restrict__ Wcv, const float* __restrict__ bcv,
                        const unsigned short* __restrict__ Wli, const float* __restrict__ bli,
                        const unsigned short* __restrict__ Wgc, const float* __restrict__ dinv,
                        unsigned short* __restrict__ NF,        // [n,128] (may alias A)
                        unsigned short* __restrict__ Q) {       // [n,128]
    constexpr int LDT = 40;
    constexpr int LDT2 = 136;
    __shared__ unsigned short As[128 * LDT];
    __shared__ unsigned short Ws[128 * LDT];
    __shared__ unsigned short SA[128 * LDT2];

    const int tid = threadIdx.x;
    const int wid = tid >> 6, lane = tid & 63;
    const int quad = lane >> 4, lrow = lane & 15;
    const int bn0 = blockIdx.x * 128;
    const int wm = (wid & 1) * 64;
    const int wn = (wid >> 1) * 64;

    // ---- stage 0: hmid = lrelu(A x Wcv^T + bcv) -> SA ----
    {
        f32x4 acc[4][4] = {};
        for (int k0 = 0; k0 < 128; k0 += 32) {
#pragma unroll
            for (int h = 0; h < 2; ++h) {
                int ch = tid + h * 256;
                int row = ch >> 2, cp = ch & 3;
                *(float4*)&As[row * LDT + cp * 8] =
                    *(const float4*)(A + (size_t)(bn0 + row) * 128 + k0 + cp * 8);
                *(float4*)&Ws[row * LDT + cp * 8] =
                    *(const float4*)(Wcv + (size_t)row * 128 + k0 + cp * 8);
            }
            __syncthreads();
            frag8 af[4], bf[4];
#pragma unroll
            for (int i = 0; i < 4; ++i)
                af[i] = *(const frag8*)&As[(wm + i * 16 + lrow) * LDT + quad * 8];
#pragma unroll
            for (int j = 0; j < 4; ++j)
                bf[j] = *(const frag8*)&Ws[(wn + j * 16 + lrow) * LDT + quad * 8];
#pragma unroll
            for (int i = 0; i < 4; ++i)
#pragma unroll
                for (int j = 0; j < 4; ++j)
                    acc[i][j] = __builtin_amdgcn_mfma_f32_16x16x32_bf16(af[i], bf[j], acc[i][j], 0, 0, 0);
            __syncthreads();
        }
#pragma unroll
        for (int j = 0; j < 4; ++j) {
            const int col = wn + j * 16 + lrow;
            float bv = bcv[col];
#pragma unroll
            for (int i = 0; i < 4; ++i) {
                const int rowl = wm + i * 16 + quad * 4;
#pragma unroll
                for (int r = 0; r < 4; ++r)
                    SA[(rowl + r) * LDT2 + col] = f2b(lrelu01(acc[i][j][r] + bv));
            }
        }
        __syncthreads();
    }
    // ---- stage 1: nf = lrelu(hmid x Wli^T + bli) -> NF global + SA (overwrite) ----
    {
        f32x4 acc[4][4] = {};
        for (int k0 = 0; k0 < 128; k0 += 32) {
#pragma unroll
            for (int h = 0; h < 2; ++h) {
                int ch = tid + h * 256;
                int row = ch >> 2, cp = ch & 3;
                *(float4*)&Ws[row * LDT + cp * 8] =
                    *(const float4*)(Wli + (size_t)row * 128 + k0 + cp * 8);
            }
            __syncthreads();
            frag8 af[4], bf[4];
#pragma unroll
            for (int i = 0; i < 4; ++i)
                af[i] = *(const frag8*)&SA[(wm + i * 16 + lrow) * LDT2 + k0 + quad * 8];
#pragma unroll
            for (int j = 0; j < 4; ++j)
                bf[j] = *(const frag8*)&Ws[(wn + j * 16 + lrow) * LDT + quad * 8];
#pragma unroll
            for (int i = 0; i < 4; ++i)
#pragma unroll
                for (int j = 0; j < 4; ++j)
                    acc[i][j] = __builtin_amdgcn_mfma_f32_16x16x32_bf16(af[i], bf[j], acc[i][j], 0, 0, 0);
            __syncthreads();
        }
#pragma unroll
        for (int j = 0; j < 4; ++j) {
            const int col = wn + j * 16 + lrow;
            float bv = bli[col];
#pragma unroll
            for (int i = 0; i < 4; ++i) {
                const int rowl = wm + i * 16 + quad * 4;
#pragma unroll
                for (int r = 0; r < 4; ++r) {
                    unsigned short h = f2b(lrelu01(acc[i][j][r] + bv));
                    NF[(size_t)(bn0 + rowl + r) * 128 + col] = h;
                    SA[(rowl + r) * LDT2 + col] = h;
                }
            }
        }
        __syncthreads();
    }
    // ---- stage 2: q = (nf x Wgc^T) * dinv -> Q ----
    {
        f32x4 acc[4][4] = {};
        for (int k0 = 0; k0 < 128; k0 += 32) {
#pragma unroll
            for (int h = 0; h < 2; ++h) {
                int ch = tid + h * 256;
                int row = ch >> 2, cp = ch & 3;
                *(float4*)&Ws[row * LDT + cp * 8] =
                    *(const float4*)(Wgc + (size_t)row * 128 + k0 + cp * 8);
            }
            __syncthreads();
            frag8 af[4], bf[4];
#pragma unroll
            for (int i = 0; i < 4; ++i)
                af[i] = *(const frag8*)&SA[(wm + i * 16 + lrow) * LDT2 + k0 + quad * 8];
#pragma unroll
            for (int j = 0; j < 4; ++j)
                bf[j] = *(const frag8*)&Ws[(wn + j * 16 + lrow) * LDT + quad * 8];
#pragma unroll
            for (int i = 0; i < 4; ++i)
#pragma unroll
                for (int j = 0; j < 4; ++j)
                    acc[i][j] = __builtin_amdgcn_mfma_f32_16x16x32_bf16(af[i], bf[j], acc[i][j], 0, 0, 0);
            __syncthreads();
        }
#pragma unroll
        for (int j = 0; j < 4; ++j) {
            const int col = wn + j * 16 + lrow;
#pragma unroll
            for (int i = 0; i < 4; ++i) {
                const int rowb = bn0 + wm + i * 16 + quad * 4;
#pragma unroll
                for (int r = 0; r < 4; ++r)
                    Q[(size_t)(rowb + r) * 128 + col] = f2b(acc[i][j][r] * dinv[rowb + r]);
            }
        }
    }
}

// out = c4 (from pooled) + xdot  — tiny
__global__ void k_out2(const float* __restrict__ xdot, const float* __restrict__ ow,
                       const float* __restrict__ ob, const float* __restrict__ pooled,
                       float* __restrict__ out, int n, float invn) {
    __shared__ float c4s[4];
    int tid = threadIdx.x;
    {
        int j = tid >> 6, lane = tid & 63;
        float s = 0.f;
        for (int c = lane; c < 256; c += 64) s += pooled[c] * invn * ow[j * 320 + c];
#pragma unroll
        for (int off = 32; off > 0; off >>= 1) s += __shfl_down(s, off);
        if (lane == 0) c4s[j] = s + ob[j];
    }
    __syncthreads();
    int node = blockIdx.x * 256 + tid;
    if (node >= n) return;
    float4 xd = *(const float4*)(xdot + (size_t)node * 4);
    *(float4*)(out + (size_t)node * 4) =
        make_float4(c4s[0] + xd.x, c4s[1] + xd.y, c4s[2] + xd.z, c4s[3] + xd.w);
}

// ================= launch =================
// Buffer lifetimes:
//   F1 [N,128]f32: z2 only
//   B1 [N,64] u16: h1 -> nf1
//   B2 [(N*128+128)]u16: A3F -> q1 (first N*64) -> q2.  The 128-entry row at
//       offset N*128 is zeroed in the prologue and never overwritten: shared
//       gather dummy row (idx 2N for CH=64 rows, idx N for CH=128 rows).
//   B3 [N,128]u16: hln1 -> nf2 (k_cligc rewrites its own rows in place)
//   H  [N,320]u16: xg cols 256.. (early), LN2 out cols 0..255 (late)
//   XD [N,4]f32:   per-node xg(dot)ow partial for the head

extern "C" void kernel_launch(void* const* d_in, const int* in_sizes, int n_in,
                              void* d_out, int out_size, void* d_ws, size_t ws_size,
                              hipStream_t stream) {
    const float* x   = (const float*)d_in[0];
    const int*   ei  = (const int*)d_in[1];
    const float* c1w = (const float*)d_in[2];  const float* c1b = (const float*)d_in[3];
    const float* c2w = (const float*)d_in[4];  const float* c2b = (const float*)d_in[5];
    const float* c3w = (const float*)d_in[6];  const float* c3b = (const float*)d_in[7];
    const float* f1w = (const float*)d_in[8];  const float* f1b = (const float*)d_in[9];
    const float* f2w = (const float*)d_in[10]; const float* f2bp = (const float*)d_in[11];
    const float* f3w = (const float*)d_in[12]; const float* f3b = (const float*)d_in[13];
    const float* cv1w = (const float*)d_in[14]; const float* cv1b = (const float*)d_in[15];
    const float* li1w = (const float*)d_in[16]; const float* li1b = (const float*)d_in[17];
    const float* gc1w = (const float*)d_in[18]; const float* gc1b = (const float*)d_in[19];
    const float* ln1g = (const float*)d_in[20]; const float* ln1b = (const float*)d_in[21];
    const float* cv2w = (const float*)d_in[22]; const float* cv2b = (const float*)d_in[23];
    const float* li2w = (const float*)d_in[24]; const float* li2b = (const float*)d_in[25];
    const float* gc2w = (const float*)d_in[26]; const float* gc2b = (const float*)d_in[27];
    const float* ln2g = (const float*)d_in[28]; const float* ln2b = (const float*)d_in[29];
    const float* cv3w = (const float*)d_in[30]; const float* cv3b = (const float*)d_in[31];
    const float* ow  = (const float*)d_in[32]; const float* ob  = (const float*)d_in[33];
    float* out = (float*)d_out;

    const int N = in_sizes[0] / 3;
    const int E = in_sizes[1] / 2;
    const int* srcI = ei;
    const int* dstI = ei + E;

    char* base = (char*)d_ws;
    size_t off = 0;
    auto take = [&](size_t bytes) -> char* {
        char* p = base + off;
        off = (off + bytes + 255) & ~(size_t)255;
        return p;
    };
    int*   deg    = (int*)  take((size_t)N * 4);
    float* sm     = (float*)take(8192 * 4);      // adjacent to deg -> single memset
    float* dinv   = (float*)take((size_t)N * 4);
    int*   startv = (int*)  take((size_t)N * 4);
    int*   rank   = (int*)  take((size_t)E * 4);
    int*   csr    = (int*)  take((size_t)E * 4);
    int*   bsum   = (int*)  take(512 * 4);
    unsigned short* WB = (unsigned short*)take(278528 * 2);
    unsigned short* H  = (unsigned short*)take((size_t)N * 320 * 2);
    float* F1 = (float*)take((size_t)N * 128 * 4);
    unsigned short* B1 = (unsigned short*)take((size_t)N * 64 * 2);
    unsigned short* B2 = (unsigned short*)take(((size_t)N * 128 + 128) * 2);
    unsigned short* B3 = (unsigned short*)take((size_t)N * 128 * 2);
    float* XD = (float*)take((size_t)N * 4 * 4);

    unsigned short* c2wb  = WB + 0;
    unsigned short* c3wf  = WB + 8192;   // fragment-order c3 weights (8 x 16384)
    unsigned short* li1wb = WB + 139264;
    unsigned short* gc1wb = WB + 143360;
    unsigned short* cv2wb = WB + 147456;
    unsigned short* li2wb = WB + 163840;
    unsigned short* gc2wb = WB + 180224;
    unsigned short* cv3wb = WB + 196608;

    float* sum2 = sm + 0;    float* ss2 = sm + 128;
    float* sum3 = sm + 256;  float* ss3 = sm + 1280;
    unsigned* maxk = (unsigned*)(sm + 2304);
    float* pooled = sm + 3328;
    unsigned* dmax = (unsigned*)(sm + 3584);   // 3584..3711
    unsigned* cnt1 = (unsigned*)(sm + 3712);
    unsigned* cnt2 = (unsigned*)(sm + 3713);
    float* T9  = sm + 3968;
    float* a1  = sm + 5120;   // 512 floats
    float* a2  = sm + 5760;   // 256 floats

    const float invn = 1.0f / (float)N;
    const dim3 blk(256);
    const unsigned GX = (unsigned)(N / 128);
    const unsigned NB = cdivu((unsigned)N, 256);
    const unsigned EB = cdivu((unsigned)E, 256);
    const unsigned WCB = cdivu(278528u, 256);
    const unsigned PB = cdivu((unsigned)N * 16, 256);
    const unsigned NZ = 8 * GX;

    // merged memset: deg (padded to 256B) + sm prefix (stats + spin counters)
    size_t degpad = ((size_t)N * 4 + 255) & ~(size_t)255;
    hipMemsetAsync(deg, 0, degpad + 3720 * 4, stream);
    // shared 256B zero row at B2 + N*128 entries (gather dummy for both glns)
    hipMemsetAsync(B2 + (size_t)N * 128, 0, 256, stream);

    // FK1: degree/rank atomics || weight pack || tnet-c1
    FK1<<<EB + WCB + NB, blk, 0, stream>>>(dstI, deg, rank, E, (int)EB,
                                           c2w, c3w, li1w, gc1w, cv2w, li2w, gc2w, cv3w,
                                           WB, (int)WCB, x, c1w, c1b, B1, N);
    // FK2: z2 GEMM (stats) || local scan + dinv
    FK2<<<GX + NB, blk, 0, stream>>>(B1, 64, 64, c2wb, c2b, F1, 128,
                                     sum2, ss2, dmax, (int)GX, deg, startv, bsum, dinv, N);
    // FK3: pre-BN repack || block-sum scan
    FK3<<<PB + 1, blk, 0, stream>>>(F1, sum2, ss2, B2, N * 16, invn, (int)PB, bsum, (int)NB);
    // FK4: z3 stats GEMM ||| CSR fill, interleaved
    FK4<<<NZ + EB, blk, 0, stream>>>(B2, c3wf, c3b, sum3, ss3, maxk, (int)NZ, (int)EB,
                                     srcI, dstI, rank, startv, bsum, csr, E);
    // TNet tail: fc1+fc2+fc3 fused via 32-block spin barriers
    k_tnet<<<32, blk, 0, stream>>>(sum3, ss3, maxk, f1w, f1b, f2w, f2bp, f3w, f3b,
                                   a1, a2, T9, cnt1, cnt2, invn);
    // xg + xdot
    k_xg2<<<NB, blk, 0, stream>>>(x, T9, cv1w, cv1b, ow, H + 256, XD, N);

    // ---- GCN block 1 (C=64) ----
    k_ligc<64><<<GX, blk, 0, stream>>>(H + 256, 320, 64, li1wb, li1b, gc1wb, dinv, B1, 64, B2, 64);
    k_gln<64><<<cdivu((unsigned)N, 4), blk, 0, stream>>>(
        startv, bsum, deg, csr, B2, B1, dinv, gc1b, ln1g, ln1b, B3, 128, N, 2 * N);

    // ---- GCN block 2 (C=128): conv2+li2+gc2 fused ----
    k_cligc<<<GX, blk, 0, stream>>>(B3, cv2wb, cv2b, li2wb, li2b, gc2wb, dinv, B3, B2);
    k_gln<128><<<cdivu((unsigned)N, 4), blk, 0, stream>>>(
        startv, bsum, deg, csr, B2, B3, dinv, gc2b, ln2g, ln2b, H, 320, N, N);

    // ---- conv3 (K=320 -> 256), SWAP grid so both col-blocks of a row-tile are adjacent ----
    k_mgemm<128, (MF_BIAS | MF_LRELU | MF_COLSUM), 1><<<dim3(2, GX), blk, 0, stream>>>(
        H, 320, 320, cv3wb, cv3b, nullptr, nullptr, 0, nullptr, pooled, nullptr, nullptr);

    // ---- head ----
    k_out2<<<NB, blk, 0, stream>>>(XD, ow, ob, pooled, out, N, invn);
}

// Round 6
// 516.944 us; speedup vs baseline: 1.2202x; 1.2202x over previous
//
#include <hip/hip_runtime.h>
#include <cstddef>

#define EPSV 1e-5f

typedef __attribute__((ext_vector_type(8))) short frag8;   // 8 bf16 (4 VGPRs)
typedef __attribute__((ext_vector_type(4))) float f32x4;   // MFMA acc

__device__ __forceinline__ float lrelu01(float v) { return v > 0.f ? v : 0.01f * v; }
__device__ __forceinline__ void atomAddF(float* p, float v) { unsafeAtomicAdd(p, v); }
__device__ __forceinline__ unsigned fkey(float f) {
    unsigned u = __float_as_uint(f);
    return (u & 0x80000000u) ? ~u : (u | 0x80000000u);
}
__device__ __forceinline__ unsigned short f2b(float f) {  // RNE float->bf16
    unsigned u = __float_as_uint(f);
    unsigned r = u + 0x7fffu + ((u >> 16) & 1u);
    return (unsigned short)(r >> 16);
}
__device__ __forceinline__ float b2f(unsigned short h) {
    return __uint_as_float(((unsigned)h) << 16);
}
__device__ __forceinline__ float blo(unsigned u) { return __uint_as_float(u << 16); }
__device__ __forceinline__ float bhi(unsigned u) { return __uint_as_float(u & 0xffff0000u); }

static inline unsigned cdivu(unsigned a, unsigned b) { return (a + b - 1) / b; }

// device-scope spin barrier for a small, fully-co-resident grid.
// cnt lives in memset-zeroed workspace; replay-after-completion is idempotent.
__device__ __forceinline__ void gbar(unsigned* cnt, unsigned target) {
    __syncthreads();
    if (threadIdx.x == 0) {
        __threadfence();
        atomicAdd(cnt, 1u);
        while (atomicAdd(cnt, 0u) < target) { }
        __threadfence();
    }
    __syncthreads();
}

// ================= graph prep bodies =================

__device__ void degrank_body(int bid, const int* __restrict__ dst, int* __restrict__ deg,
                             int* __restrict__ rank, int E) {
    int e = bid * 256 + threadIdx.x;
    if (e < E) rank[e] = atomicAdd(&deg[dst[e]], 1);
}

__device__ void scan_local_body(int bid, const int* __restrict__ deg, int* __restrict__ startv,
                                int* __restrict__ bsum, float* __restrict__ dinv, int n) {
    __shared__ int t0[256];
    int tid = threadIdx.x;
    int i = bid * 256 + tid;
    int v = (i < n) ? deg[i] : 0;
    if (i < n) dinv[i] = rsqrtf((float)(v + 1));  // +1 self loop
    t0[tid] = v;
    __syncthreads();
    for (int o = 1; o < 256; o <<= 1) {
        int add = (tid >= o) ? t0[tid - o] : 0;
        __syncthreads();
        t0[tid] += add;
        __syncthreads();
    }
    if (i < n) startv[i] = t0[tid] - v;
    if (tid == 255) bsum[bid] = t0[255];
}

// 256-thread scan over up to 512 block sums (ping-pong Hillis-Steele)
__device__ void scan_bsum_body(int* __restrict__ bsum, int nb) {
    __shared__ int t0[512];
    __shared__ int t1[512];
    int tid = threadIdx.x;
    int v0 = (tid < nb) ? bsum[tid] : 0;
    int v1 = (tid + 256 < nb) ? bsum[tid + 256] : 0;
    t0[tid] = v0; t0[tid + 256] = v1;
    __syncthreads();
    int* a = t0; int* b = t1;
    for (int o = 1; o < 512; o <<= 1) {
        b[tid]       = a[tid]       + ((tid >= o)       ? a[tid - o]       : 0);
        b[tid + 256] = a[tid + 256] + ((tid + 256 >= o) ? a[tid + 256 - o] : 0);
        __syncthreads();
        int* t = a; a = b; b = t;
    }
    if (tid < nb) bsum[tid] = a[tid] - v0;
    if (tid + 256 < nb) bsum[tid + 256] = a[tid + 256] - v1;
}

// fill using local startv + block-prefix bsum (no scan_add pass needed)
__device__ void fill_body(int bid, const int* __restrict__ src, const int* __restrict__ dst,
                          const int* __restrict__ rank, const int* __restrict__ startv,
                          const int* __restrict__ bsum, int* __restrict__ csr, int E) {
    int e = bid * 256 + threadIdx.x;
    if (e < E) {
        int d = dst[e];
        csr[startv[d] + bsum[d >> 8] + rank[e]] = src[e];
    }
}

// ================= small bodies =================

__device__ void wconv_body(int bid, const float* __restrict__ s0, const float* __restrict__ s1,
                           const float* __restrict__ s2, const float* __restrict__ s3,
                           const float* __restrict__ s4, const float* __restrict__ s5,
                           const float* __restrict__ s6, const float* __restrict__ s7,
                           unsigned short* __restrict__ dst) {
    int t = bid * 256 + threadIdx.x;
    if (t >= 278528) return;
    const float* srcs[8] = {s0, s1, s2, s3, s4, s5, s6, s7};
    const int off[9] = {0, 8192, 139264, 143360, 147456, 163840, 180224, 196608, 278528};
    int seg = 0;
    while (t >= off[seg + 1]) ++seg;
    unsigned short v = f2b(srcs[seg][t - off[seg]]);
    if (seg == 1) {
        int li = t - 8192;
        int rch = li >> 7, k = li & 127;
        int cb = rch >> 7, r = rch & 127;
        int flat = ((r >> 4) * 4 + (k >> 5)) * 64 + ((k >> 3) & 3) * 16 + (r & 15);
        dst[8192 + cb * 16384 + flat * 8 + (k & 7)] = v;
    } else {
        dst[t] = v;
    }
}

__device__ void h1_body(int bid, const float* __restrict__ x, const float* __restrict__ w,
                        const float* __restrict__ b, unsigned short* __restrict__ h1, int n) {
    int node = bid * 256 + threadIdx.x;
    if (node >= n) return;
    float x0 = x[node * 3], x1 = x[node * 3 + 1], x2 = x[node * 3 + 2];
    unsigned short* o = h1 + (size_t)node * 64;
#pragma unroll
    for (int cp = 0; cp < 8; ++cp) {
        unsigned short tmp[8];
#pragma unroll
        for (int t = 0; t < 8; ++t) {
            int c = cp * 8 + t;
            float v = x0 * w[c * 3] + x1 * w[c * 3 + 1] + x2 * w[c * 3 + 2] + b[c];
            tmp[t] = f2b(fmaxf(v, 0.f));
        }
        *(float4*)(o + cp * 8) = *(float4*)tmp;
    }
}

__device__ void prebn_body(int bid, const float* __restrict__ z, const float* __restrict__ sum2,
                           const float* __restrict__ ss2, unsigned short* __restrict__ a3f,
                           int n16, float invn) {
    int t = bid * 256 + threadIdx.x;
    if (t >= n16) return;
    int row = t >> 4, cp = t & 15;
    int c = cp * 8;
    const float* src = z + (size_t)row * 128 + c;
    float4 v0 = *(const float4*)src;
    float4 v1 = *(const float4*)(src + 4);
    float vv[8] = {v0.x, v0.y, v0.z, v0.w, v1.x, v1.y, v1.z, v1.w};
    unsigned short o[8];
#pragma unroll
    for (int i = 0; i < 8; ++i) {
        float m = sum2[c + i] * invn;
        float var = ss2[c + i] * invn - m * m;
        o[i] = f2b(fmaxf((vv[i] - m) * rsqrtf(var + EPSV), 0.f));
    }
    int tile = row >> 7, r = row & 127;
    int flat = ((r >> 4) * 4 + (cp >> 2)) * 64 + (cp & 3) * 16 + (r & 15);
    *(float4*)(a3f + (size_t)tile * 16384 + flat * 8) = *(float4*)o;
}

// ================= MFMA GEMM body (generic, BK=32) =================
enum { MF_BIAS = 1, MF_LRELU = 2, MF_DINV = 4, MF_STOREF = 8, MF_STOREB = 16,
       MF_STATS = 32, MF_COLSUM = 64 };

template <int BN, int MODE>
__device__ void mgemm_body(int bx, int by,
                           const unsigned short* __restrict__ A, int lda, int K,
                           const unsigned short* __restrict__ W,  // [C][K]
                           const float* __restrict__ bias,
                           float* __restrict__ OutF, unsigned short* __restrict__ OutB, int ldo,
                           const float* __restrict__ dinv,
                           float* __restrict__ sum_o, float* __restrict__ ss_o,
                           unsigned* __restrict__ maxk_o) {
    constexpr int BM = 128;
    constexpr int LDT = 40;
    __shared__ unsigned short As[BM * LDT];
    __shared__ unsigned short Ws[BN * LDT];
    __shared__ float redS[2 * 128];
    __shared__ unsigned redM[128];

    const int tid = threadIdx.x;
    const int wid = tid >> 6, lane = tid & 63;
    const int quad = lane >> 4, lrow = lane & 15;
    const int bn0 = bx * BM;
    const int bc0 = by * BN;

    constexpr int NI = (BN == 128) ? 4 : 2;
    constexpr int NJ = 4;
    const int wm = (BN == 128) ? (wid & 1) * 64 : wid * 32;
    const int wn = (BN == 128) ? (wid >> 1) * 64 : 0;

    if (MODE & (MF_STATS | MF_COLSUM)) {
        for (int c = tid; c < BN; c += 256) {
            redS[c] = 0.f; redS[128 + c] = 0.f; redM[c] = 0u;
        }
    }

    f32x4 acc[NI][NJ] = {};

    for (int k0 = 0; k0 < K; k0 += 32) {
#pragma unroll
        for (int h = 0; h < 2; ++h) {
            int ch = tid + h * 256;
            int row = ch >> 2, cp = ch & 3;
            const unsigned short* src = A + (size_t)(bn0 + row) * lda + k0 + cp * 8;
            *(float4*)&As[row * LDT + cp * 8] = *(const float4*)src;
        }
#pragma unroll
        for (int h = 0; h < BN / 64; ++h) {
            int ch = tid + h * 256;
            int row = ch >> 2, cp = ch & 3;
            const unsigned short* src = W + (size_t)(bc0 + row) * K + k0 + cp * 8;
            *(float4*)&Ws[row * LDT + cp * 8] = *(const float4*)src;
        }
        __syncthreads();
        frag8 af[NI], bf[NJ];
#pragma unroll
        for (int i = 0; i < NI; ++i)
            af[i] = *(const frag8*)&As[(wm + i * 16 + lrow) * LDT + quad * 8];
#pragma unroll
        for (int j = 0; j < NJ; ++j)
            bf[j] = *(const frag8*)&Ws[(wn + j * 16 + lrow) * LDT + quad * 8];
#pragma unroll
        for (int i = 0; i < NI; ++i)
#pragma unroll
            for (int j = 0; j < NJ; ++j)
                acc[i][j] = __builtin_amdgcn_mfma_f32_16x16x32_bf16(af[i], bf[j], acc[i][j], 0, 0, 0);
        __syncthreads();
    }

#pragma unroll
    for (int j = 0; j < NJ; ++j) {
        const int col = bc0 + wn + j * 16 + lrow;
        float bv = (MODE & MF_BIAS) ? bias[col] : 0.f;
        float s = 0.f, q = 0.f, m = -3.4e38f;
#pragma unroll
        for (int i = 0; i < NI; ++i) {
            const int rowb = bn0 + wm + i * 16 + quad * 4;
#pragma unroll
            for (int r = 0; r < 4; ++r) {
                float t = acc[i][j][r] + bv;
                if (MODE & MF_LRELU) t = lrelu01(t);
                if (MODE & MF_DINV) t *= dinv[rowb + r];
                if (MODE & MF_STOREF) OutF[(size_t)(rowb + r) * ldo + col] = t;
                if (MODE & MF_STOREB) OutB[(size_t)(rowb + r) * ldo + col] = f2b(t);
                s += t; q += t * t; m = fmaxf(m, t);
            }
        }
        if (MODE & (MF_STATS | MF_COLSUM)) {
            s += __shfl_xor(s, 16); s += __shfl_xor(s, 32);
            if (MODE & MF_STATS) {
                q += __shfl_xor(q, 16); q += __shfl_xor(q, 32);
                m = fmaxf(m, __shfl_xor(m, 16)); m = fmaxf(m, __shfl_xor(m, 32));
            }
            if (quad == 0) {
                int lc = wn + j * 16 + lrow;
                atomicAdd(&redS[lc], s);
                if (MODE & MF_STATS) {
                    atomicAdd(&redS[128 + lc], q);
                    atomicMax(&redM[lc], fkey(m));
                }
            }
        }
    }
    if (MODE & (MF_STATS | MF_COLSUM)) {
        __syncthreads();
        for (int c = tid; c < BN; c += 256) {
            atomAddF(&sum_o[bc0 + c], redS[c]);
            if (MODE & MF_STATS) {
                atomAddF(&ss_o[bc0 + c], redS[128 + c]);
                atomicMax(&maxk_o[bc0 + c], redM[c]);
            }
        }
    }
}

// standalone GEMM wrapper; SWAP=1 maps row-tile to blockIdx.y so the two
// column-blocks of one row-tile are dispatch-adjacent (A tile L2-hit).
template <int BN, int MODE, int SWAP>
__launch_bounds__(256)
__global__ void k_mgemm(const unsigned short* __restrict__ A, int lda, int K,
                        const unsigned short* __restrict__ W,
                        const float* __restrict__ bias,
                        float* __restrict__ OutF, unsigned short* __restrict__ OutB, int ldo,
                        const float* __restrict__ dinv,
                        float* __restrict__ sum_o, float* __restrict__ ss_o,
                        unsigned* __restrict__ maxk_o) {
    int bx = SWAP ? blockIdx.y : blockIdx.x;
    int by = SWAP ? blockIdx.x : blockIdx.y;
    mgemm_body<BN, MODE>(bx, by, A, lda, K, W, bias, OutF, OutB, ldo, dinv, sum_o, ss_o, maxk_o);
}

// ================= z3 stats GEMM: no LDS, no barrier =================
// tile = bid>>3: 8 consecutive z3 indices share one 32KB A tile (L2 reuse).
__device__ void z3_body(int bid,
                        const unsigned short* __restrict__ AF,
                        const unsigned short* __restrict__ WF,
                        const float* __restrict__ bias,
                        float* __restrict__ sum_o, float* __restrict__ ss_o,
                        unsigned* __restrict__ maxk_o) {
    const int tid = threadIdx.x;
    const int wid = tid >> 6, lane = tid & 63;
    const int quad = lane >> 4, lrow = lane & 15;

    const int tile = bid >> 3;
    const int cb = bid & 7;
    const unsigned short* At = AF + (size_t)tile * 16384;
    const unsigned short* Wt = WF + (size_t)cb * 16384;

    const int ar = (wid & 1) * 4;
    const int wc = (wid >> 1) * 4;
    f32x4 acc[4][4] = {};
#pragma unroll
    for (int kc = 0; kc < 4; ++kc) {
        frag8 af[4], bf[4];
#pragma unroll
        for (int i = 0; i < 4; ++i)
            af[i] = *(const frag8*)&At[(((ar + i) * 4 + kc) * 64 + lane) * 8];
#pragma unroll
        for (int j = 0; j < 4; ++j)
            bf[j] = *(const frag8*)&Wt[(((wc + j) * 4 + kc) * 64 + lane) * 8];
#pragma unroll
        for (int i = 0; i < 4; ++i)
#pragma unroll
            for (int j = 0; j < 4; ++j)
                acc[i][j] = __builtin_amdgcn_mfma_f32_16x16x32_bf16(af[i], bf[j], acc[i][j], 0, 0, 0);
    }

#pragma unroll
    for (int j = 0; j < 4; ++j) {
        int c = cb * 128 + (wc + j) * 16 + lrow;
        float bv = bias[c];
        float s = 0.f, q = 0.f, m = -3.4e38f;
#pragma unroll
        for (int i = 0; i < 4; ++i)
#pragma unroll
            for (int r = 0; r < 4; ++r) {
                float t = acc[i][j][r] + bv;
                s += t; q += t * t; m = fmaxf(m, t);
            }
        s += __shfl_xor(s, 16); s += __shfl_xor(s, 32);
        q += __shfl_xor(q, 16); q += __shfl_xor(q, 32);
        m = fmaxf(m, __shfl_xor(m, 16)); m = fmaxf(m, __shfl_xor(m, 32));
        if (quad == 0) {
            atomAddF(&sum_o[c], s);
            atomAddF(&ss_o[c], q);
            atomicMax(&maxk_o[c], fkey(m));
        }
    }
}

// ================= fat kernels =================

__launch_bounds__(256)
__global__ void FK1(const int* __restrict__ dst, int* __restrict__ deg, int* __restrict__ rank,
                    int E, int EB,
                    const float* s0, const float* s1, const float* s2, const float* s3,
                    const float* s4, const float* s5, const float* s6, const float* s7,
                    unsigned short* __restrict__ WB, int WCB,
                    const float* __restrict__ x, const float* __restrict__ c1w,
                    const float* __restrict__ c1b, unsigned short* __restrict__ B1, int n) {
    int b = blockIdx.x;
    if (b < EB) { degrank_body(b, dst, deg, rank, E); return; }
    b -= EB;
    if (b < WCB) { wconv_body(b, s0, s1, s2, s3, s4, s5, s6, s7, WB); return; }
    b -= WCB;
    h1_body(b, x, c1w, c1b, B1, n);
}

__launch_bounds__(256)
__global__ void FK2(const unsigned short* __restrict__ A, int lda, int K,
                    const unsigned short* __restrict__ W, const float* __restrict__ bias,
                    float* __restrict__ OutF, int ldo,
                    float* __restrict__ sum_o, float* __restrict__ ss_o,
                    unsigned* __restrict__ maxk_o, int GXz,
                    const int* __restrict__ deg, int* __restrict__ startv,
                    int* __restrict__ bsum, float* __restrict__ dinvv, int n) {
    if ((int)blockIdx.x < GXz)
        mgemm_body<128, (MF_BIAS | MF_STOREF | MF_STATS)>(
            blockIdx.x, 0, A, lda, K, W, bias, OutF, nullptr, ldo, nullptr, sum_o, ss_o, maxk_o);
    else
        scan_local_body(blockIdx.x - GXz, deg, startv, bsum, dinvv, n);
}

__launch_bounds__(256)
__global__ void FK3(const float* __restrict__ z, const float* __restrict__ sum2,
                    const float* __restrict__ ss2, unsigned short* __restrict__ a3f,
                    int n16, float invn, int PB, int* __restrict__ bsum, int nb) {
    if ((int)blockIdx.x < PB) prebn_body(blockIdx.x, z, sum2, ss2, a3f, n16, invn);
    else scan_bsum_body(bsum, nb);
}

// FK4: z3 stats GEMM ||| CSR fill, parity-interleaved, SINGLE CALL SITE per body.
// Round-5 lesson: duplicating the body calls across branch arms doubled inlining
// and blew regalloc to 144 VGPR -> 6.7% occupancy -> 3x slowdown. Compute the
// (dofill, idx) mapping first, then branch exactly once.
__launch_bounds__(256)
__global__ void FK4(const unsigned short* __restrict__ AF, const unsigned short* __restrict__ WF,
                    const float* __restrict__ bias,
                    float* __restrict__ sum_o, float* __restrict__ ss_o,
                    unsigned* __restrict__ maxk_o, int NZ, int EB,
                    const int* __restrict__ src, const int* __restrict__ dst,
                    const int* __restrict__ rank, const int* __restrict__ startv,
                    const int* __restrict__ bsum, int* __restrict__ csr, int E) {
    int b = blockIdx.x;
    int mn = (NZ < EB) ? NZ : EB;
    bool dofill;
    int idx;
    if (b < 2 * mn) {
        dofill = (b & 1) != 0;
        idx = b >> 1;
    } else if (NZ > EB) {
        dofill = false;
        idx = b - EB;
    } else {
        dofill = true;
        idx = b - NZ;
    }
    if (dofill) fill_body(idx, src, dst, rank, startv, bsum, csr, E);
    else        z3_body(idx, AF, WF, bias, sum_o, ss_o, maxk_o);
}

// k_tnet: fc1 + fc2 + fc3 in ONE 32-block kernel with device spin barriers.
// 32 blocks trivially co-resident; counters zeroed by the per-iteration memset.
__launch_bounds__(256)
__global__ void k_tnet(const float* __restrict__ sum3, const float* __restrict__ ss3,
                       const unsigned* __restrict__ maxk,
                       const float* __restrict__ f1w, const float* __restrict__ f1b,
                       const float* __restrict__ f2w, const float* __restrict__ f2bias,
                       const float* __restrict__ f3w, const float* __restrict__ f3b,
                       float* __restrict__ a1, float* __restrict__ a2,
                       float* __restrict__ T9,
                       unsigned* __restrict__ cnt1, unsigned* __restrict__ cnt2, float invn) {
    __shared__ float g[1024];
    __shared__ float a1s[512];
    int tid = threadIdx.x;
    int bid = blockIdx.x;
    // ---- g = relu(bn(maxpool)) ----
    for (int c = tid; c < 1024; c += 256) {
        float m = sum3[c] * invn;
        float var = ss3[c] * invn - m * m;
        unsigned k = maxk[c];
        unsigned u = (k & 0x80000000u) ? (k & 0x7FFFFFFFu) : ~k;
        g[c] = fmaxf((__uint_as_float(u) - m) * rsqrtf(var + EPSV), 0.f);
    }
    __syncthreads();
    // ---- fc1: 16 rows/block, 16 lanes/row ----
    {
        int row = bid * 16 + (tid >> 4);
        int part = tid & 15;
        const float* w = f1w + (size_t)row * 1024 + part * 64;
        const float* gg = g + part * 64;
        float s = 0.f;
#pragma unroll 4
        for (int k = 0; k < 64; k += 4) {
            float4 wv = *(const float4*)(w + k);
            s = fmaf(wv.x, gg[k], s);
            s = fmaf(wv.y, gg[k + 1], s);
            s = fmaf(wv.z, gg[k + 2], s);
            s = fmaf(wv.w, gg[k + 3], s);
        }
        s += __shfl_xor(s, 1); s += __shfl_xor(s, 2);
        s += __shfl_xor(s, 4); s += __shfl_xor(s, 8);
        if (part == 0) a1[row] = fmaxf(s + f1b[row], 0.f);
    }
    gbar(cnt1, 32);
    // ---- fc2: 8 rows/block, 32 lanes/row ----
    a1s[tid] = a1[tid];
    a1s[tid + 256] = a1[tid + 256];
    __syncthreads();
    {
        int row = bid * 8 + (tid >> 5);
        int part = tid & 31;
        const float* w = f2w + (size_t)row * 512 + part * 16;
        const float* aa = a1s + part * 16;
        float s = 0.f;
#pragma unroll
        for (int k = 0; k < 16; k += 4) {
            float4 wv = *(const float4*)(w + k);
            s = fmaf(wv.x, aa[k], s);
            s = fmaf(wv.y, aa[k + 1], s);
            s = fmaf(wv.z, aa[k + 2], s);
            s = fmaf(wv.w, aa[k + 3], s);
        }
        s += __shfl_xor(s, 1); s += __shfl_xor(s, 2); s += __shfl_xor(s, 4);
        s += __shfl_xor(s, 8); s += __shfl_xor(s, 16);
        if (part == 0) a2[row] = fmaxf(s + f2bias[row], 0.f);
    }
    gbar(cnt2, 32);
    // ---- fc3 (block 0): 9 rows, 16 lanes/row ----
    if (bid == 0 && tid < 144) {
        int r = tid >> 4, kk = (tid & 15) * 16;
        const float* wr = f3w + r * 256 + kk;
        float s = 0.f;
#pragma unroll
        for (int k = 0; k < 16; ++k) s = fmaf(wr[k], a2[kk + k], s);
        s += __shfl_xor(s, 1); s += __shfl_xor(s, 2);
        s += __shfl_xor(s, 4); s += __shfl_xor(s, 8);
        if ((tid & 15) == 0) {
            s += f3b[r];
            if (r == 0 || r == 4 || r == 8) s += 1.f;
            T9[r] = s;
        }
    }
}

// ================= fused gather + LN =================
// nd = dummy row index (points at the shared 256B zero row at B2 + N*128 entries:
// nd = 2N when q rows are 64ch, nd = N when 128ch).
template <int CH>
__launch_bounds__(256)
__global__ void k_gln(const int* __restrict__ startv, const int* __restrict__ bsum,
                      const int* __restrict__ degv,
                      const int* __restrict__ csr, const unsigned short* __restrict__ q,
                      const unsigned short* __restrict__ nf, const float* __restrict__ dinv,
                      const float* __restrict__ gcn_b, const float* __restrict__ lng,
                      const float* __restrict__ lnb, unsigned short* __restrict__ outp,
                      int ldo, int n, int nd) {
    constexpr int GRP = (CH == 64) ? 8 : 4;   // rows in flight per load instr
    constexpr int PL  = 64 / GRP;             // lanes per row slice
    constexpr int TT  = 16 / GRP;             // load instrs per 16-edge chunk
    constexpr int CPL = CH / PL;              // = 8 channels per lane
    const int wv = threadIdx.x >> 6, lane = threadIdx.x & 63;
    const int g = lane / PL, p = lane & (PL - 1);
    int node = blockIdx.x * 4 + wv;
    if (node >= n) return;

    const unsigned short* qp = q + (size_t)p * CPL;

    float acc[CPL];
    {
        uint4 v = *(const uint4*)(qp + (size_t)node * CH);
        unsigned sv[4] = {v.x, v.y, v.z, v.w};
        if (g == 0) {
#pragma unroll
            for (int d = 0; d < 4; ++d) { acc[2 * d] = blo(sv[d]); acc[2 * d + 1] = bhi(sv[d]); }
        } else {
#pragma unroll
            for (int k = 0; k < CPL; ++k) acc[k] = 0.f;
        }
    }

    int s0 = startv[node] + bsum[node >> 8], cnt = degv[node];
    const int* cs = csr + s0;
    int sidx[TT];
#pragma unroll
    for (int t = 0; t < TT; ++t) { int j = t * GRP + g; sidx[t] = (j < cnt) ? cs[j] : nd; }
    for (int j0 = 0; j0 < cnt; j0 += 16) {
        uint4 buf[TT];
#pragma unroll
        for (int t = 0; t < TT; ++t)
            buf[t] = *(const uint4*)(qp + (size_t)(unsigned)sidx[t] * CH);
#pragma unroll
        for (int t = 0; t < TT; ++t) {
            int j = j0 + 16 + t * GRP + g;
            sidx[t] = (j < cnt) ? cs[j] : nd;
        }
#pragma unroll
        for (int t = 0; t < TT; ++t) {
            unsigned bw[4] = {buf[t].x, buf[t].y, buf[t].z, buf[t].w};
#pragma unroll
            for (int d = 0; d < 4; ++d) {
                acc[2 * d] += blo(bw[d]);
                acc[2 * d + 1] += bhi(bw[d]);
            }
        }
    }

#pragma unroll
    for (int k = 0; k < CPL; ++k) {
#pragma unroll
        for (int off = PL; off < 64; off <<= 1) acc[k] += __shfl_xor(acc[k], off);
    }

    float di = dinv[node];
    float nv[CPL], bv[CPL];
    {
        uint4 v = *(const uint4*)(nf + (size_t)node * CH + p * CPL);
        unsigned sv[4] = {v.x, v.y, v.z, v.w};
#pragma unroll
        for (int d = 0; d < 4; ++d) { nv[2 * d] = blo(sv[d]); nv[2 * d + 1] = bhi(sv[d]); }
    }
    const float* gb = gcn_b + p * CPL;
#pragma unroll
    for (int k = 0; k < CPL; ++k) bv[k] = lrelu01(di * acc[k] + gb[k]);

    float s = 0.f, ss = 0.f;
#pragma unroll
    for (int k = 0; k < CPL; ++k) { s += nv[k] + bv[k]; ss += nv[k] * nv[k] + bv[k] * bv[k]; }
#pragma unroll
    for (int off = 32; off > 0; off >>= 1) { s += __shfl_xor(s, off); ss += __shfl_xor(ss, off); }
    const float inv = 1.f / (float)(GRP * 2 * CH);  // GRP-way replication * 2*CH channels
    float mu = s * inv;
    float var = ss * inv - mu * mu;
    float rsg = rsqrtf(var + EPSV);

    unsigned short* orow = outp + (size_t)node * ldo;
    if (g == 0) {
        unsigned short tmp[CPL];
        const float* lg = lng + p * CPL; const float* lb = lnb + p * CPL;
#pragma unroll
        for (int k = 0; k < CPL; ++k) tmp[k] = f2b((nv[k] - mu) * rsg * lg[k] + lb[k]);
        *(uint4*)(orow + p * CPL) = *(uint4*)tmp;
    } else if (g == 1) {
        unsigned short tmp[CPL];
        const float* lg = lng + CH + p * CPL; const float* lb = lnb + CH + p * CPL;
#pragma unroll
        for (int k = 0; k < CPL; ++k) tmp[k] = f2b((bv[k] - mu) * rsg * lg[k] + lb[k]);
        *(uint4*)(orow + CH + p * CPL) = *(uint4*)tmp;
    }
}

// ================= remaining standalone kernels =================

// xg from T9; also emits xdot[node] = xg_row(dot)ow[:,256:320]
__launch_bounds__(256)
__global__ void k_xg2(const float* __restrict__ x, const float* __restrict__ T9,
                      const float* __restrict__ w, const float* __restrict__ b,
                      const float* __restrict__ ow,
                      unsigned short* __restrict__ xg, float* __restrict__ xdot, int n) {
    __shared__ float owS[256];
    __shared__ float T9s[9];
    int tid = threadIdx.x;
    owS[tid] = ow[(tid >> 6) * 320 + 256 + (tid & 63)];
    if (tid < 9) T9s[tid] = T9[tid];
    __syncthreads();
    int node = blockIdx.x * 256 + tid;
    if (node >= n) return;
    float x0 = x[node * 3], x1 = x[node * 3 + 1], x2 = x[node * 3 + 2];
    float h0 = x0 * T9s[0] + x1 * T9s[3] + x2 * T9s[6];
    float h1 = x0 * T9s[1] + x1 * T9s[4] + x2 * T9s[7];
    float h2 = x0 * T9s[2] + x1 * T9s[5] + x2 * T9s[8];
    unsigned short* o = xg + (size_t)node * 320;
    float d0 = 0.f, d1 = 0.f, d2 = 0.f, d3 = 0.f;
#pragma unroll
    for (int cp = 0; cp < 8; ++cp) {
        unsigned short tmp[8];
#pragma unroll
        for (int t = 0; t < 8; ++t) {
            int c = cp * 8 + t;
            float v = lrelu01(h0 * w[c * 3] + h1 * w[c * 3 + 1] + h2 * w[c * 3 + 2] + b[c]);
            tmp[t] = f2b(v);
            d0 = fmaf(v, owS[c], d0);
            d1 = fmaf(v, owS[64 + c], d1);
            d2 = fmaf(v, owS[128 + c], d2);
            d3 = fmaf(v, owS[192 + c], d3);
        }
        *(float4*)(o + cp * 8) = *(float4*)tmp;
    }
    *(float4*)(xdot + (size_t)node * 4) = make_float4(d0, d1, d2, d3);
}

// ---------------- fused li+gc (block 1, BN=64) ----------------
template <int BN>
__launch_bounds__(256)
__global__ void k_ligc(const unsigned short* __restrict__ A, int lda, int K,
                       const unsigned short* __restrict__ Wli, const float* __restrict__ bli,
                       const unsigned short* __restrict__ Wgc, const float* __restrict__ dinv,
                       unsigned short* __restrict__ NF, int ldnf,
                       unsigned short* __restrict__ Q, int ldq) {
    constexpr int BM = 128;
    constexpr int LDT = 40;
    constexpr int LDT2 = BN + 8;
    __shared__ unsigned short SA[BM * LDT2];
    __shared__ unsigned short Ws[BN * LDT];
    __shared__ unsigned short As[BM * LDT];

    const int tid = threadIdx.x;
    const int wid = tid >> 6, lane = tid & 63;
    const int quad = lane >> 4, lrow = lane & 15;
    const int bn0 = blockIdx.x * BM;
    constexpr int NI = (BN == 128) ? 4 : 2;
    constexpr int NJ = 4;
    const int wm = (BN == 128) ? (wid & 1) * 64 : wid * 32;
    const int wn = (BN == 128) ? (wid >> 1) * 64 : 0;

    // ---- stage 1: nf = lrelu(A x Wli^T + bli) -> NF global + SA ----
    {
        f32x4 acc[NI][NJ] = {};
        for (int k0 = 0; k0 < K; k0 += 32) {
#pragma unroll
            for (int h = 0; h < 2; ++h) {
                int ch = tid + h * 256;
                int row = ch >> 2, cp = ch & 3;
                *(float4*)&As[row * LDT + cp * 8] =
                    *(const float4*)(A + (size_t)(bn0 + row) * lda + k0 + cp * 8);
            }
#pragma unroll
            for (int h = 0; h < BN / 64; ++h) {
                int ch = tid + h * 256;
                int row = ch >> 2, cp = ch & 3;
                *(float4*)&Ws[row * LDT + cp * 8] =
                    *(const float4*)(Wli + (size_t)row * K + k0 + cp * 8);
            }
            __syncthreads();
            frag8 af[NI], bf[NJ];
#pragma unroll
            for (int i = 0; i < NI; ++i)
                af[i] = *(const frag8*)&As[(wm + i * 16 + lrow) * LDT + quad * 8];
#pragma unroll
            for (int j = 0; j < NJ; ++j)
                bf[j] = *(const frag8*)&Ws[(wn + j * 16 + lrow) * LDT + quad * 8];
#pragma unroll
            for (int i = 0; i < NI; ++i)
#pragma unroll
                for (int j = 0; j < NJ; ++j)
                    acc[i][j] = __builtin_amdgcn_mfma_f32_16x16x32_bf16(af[i], bf[j], acc[i][j], 0, 0, 0);
            __syncthreads();
        }
#pragma unroll
        for (int j = 0; j < NJ; ++j) {
            const int col = wn + j * 16 + lrow;
            float bv = bli[col];
#pragma unroll
            for (int i = 0; i < NI; ++i) {
                const int rowl = wm + i * 16 + quad * 4;
#pragma unroll
                for (int r = 0; r < 4; ++r) {
                    unsigned short h = f2b(lrelu01(acc[i][j][r] + bv));
                    NF[(size_t)(bn0 + rowl + r) * ldnf + col] = h;
                    SA[(rowl + r) * LDT2 + col] = h;
                }
            }
        }
        __syncthreads();
    }
    // ---- stage 2: q = (nf x Wgc^T) * dinv -> Q ----
    {
        f32x4 acc[NI][NJ] = {};
        for (int k0 = 0; k0 < BN; k0 += 32) {
#pragma unroll
            for (int h = 0; h < BN / 64; ++h) {
                int ch = tid + h * 256;
                int row = ch >> 2, cp = ch & 3;
                *(float4*)&Ws[row * LDT + cp * 8] =
                    *(const float4*)(Wgc + (size_t)row * BN + k0 + cp * 8);
            }
            __syncthreads();
            frag8 af[NI], bf[NJ];
#pragma unroll
            for (int i = 0; i < NI; ++i)
                af[i] = *(const frag8*)&SA[(wm + i * 16 + lrow) * LDT2 + k0 + quad * 8];
#pragma unroll
            for (int j = 0; j < NJ; ++j)
                bf[j] = *(const frag8*)&Ws[(wn + j * 16 + lrow) * LDT + quad * 8];
#pragma unroll
            for (int i = 0; i < NI; ++i)
#pragma unroll
                for (int j = 0; j < NJ; ++j)
                    acc[i][j] = __builtin_amdgcn_mfma_f32_16x16x32_bf16(af[i], bf[j], acc[i][j], 0, 0, 0);
            __syncthreads();
        }
#pragma unroll
        for (int j = 0; j < NJ; ++j) {
            const int col = wn + j * 16 + lrow;
#pragma unroll
            for (int i = 0; i < NI; ++i) {
                const int rowb = bn0 + wm + i * 16 + quad * 4;
#pragma unroll
                for (int r = 0; r < 4; ++r) {
                    float t = acc[i][j][r] * dinv[rowb + r];
                    Q[(size_t)(rowb + r) * ldq + col] = f2b(t);
                }
            }
        }
    }
}

// ---------------- fused conv2 + li2 + gc2 (block 2): 3-stage GEMM chain ----------------
// hmid = lrelu(A x Wcv^T + bcv) lives only in LDS; nf overwrites it in-place.
// A (hln1) and NF share the same buffer: each block fully consumes its global A
// rows in stage 0 before overwriting them (stage 1), and touches only own rows.
__launch_bounds__(256)
__global__ void k_cligc(const unsigned short* __restrict__ A,   // [n,128] hln1
                        const unsigned short* __restrict__ Wcv, const float* __restrict__ bcv,
                        const unsigned short* __restrict__ Wli, const float* __restrict__ bli,
                        const unsigned short* __restrict__ Wgc, const float* __restrict__ dinv,
                        unsigned short* __restrict__ NF,        // [n,128] (may alias A)
                        unsigned short* __restrict__ Q) {       // [n,128]
    constexpr int LDT = 40;
    constexpr int LDT2 = 136;
    __shared__ unsigned short As[128 * LDT];
    __shared__ unsigned short Ws[128 * LDT];
    __shared__ unsigned short SA[128 * LDT2];

    const int tid = threadIdx.x;
    const int wid = tid >> 6, lane = tid & 63;
    const int quad = lane >> 4, lrow = lane & 15;
    const int bn0 = blockIdx.x * 128;
    const int wm = (wid & 1) * 64;
    const int wn = (wid >> 1) * 64;

    // ---- stage 0: hmid = lrelu(A x Wcv^T + bcv) -> SA ----
    {
        f32x4 acc[4][4] = {};
        for (int k0 = 0; k0 < 128; k0 += 32) {
#pragma unroll
            for (int h = 0; h < 2; ++h) {
                int ch = tid + h * 256;
                int row = ch >> 2, cp = ch & 3;
                *(float4*)&As[row * LDT + cp * 8] =
                    *(const float4*)(A + (size_t)(bn0 + row) * 128 + k0 + cp * 8);
                *(float4*)&Ws[row * LDT + cp * 8] =
                    *(const float4*)(Wcv + (size_t)row * 128 + k0 + cp * 8);
            }
            __syncthreads();
            frag8 af[4], bf[4];
#pragma unroll
            for (int i = 0; i < 4; ++i)
                af[i] = *(const frag8*)&As[(wm + i * 16 + lrow) * LDT + quad * 8];
#pragma unroll
            for (int j = 0; j < 4; ++j)
                bf[j] = *(const frag8*)&Ws[(wn + j * 16 + lrow) * LDT + quad * 8];
#pragma unroll
            for (int i = 0; i < 4; ++i)
#pragma unroll
                for (int j = 0; j < 4; ++j)
                    acc[i][j] = __builtin_amdgcn_mfma_f32_16x16x32_bf16(af[i], bf[j], acc[i][j], 0, 0, 0);
            __syncthreads();
        }
#pragma unroll
        for (int j = 0; j < 4; ++j) {
            const int col = wn + j * 16 + lrow;
            float bv = bcv[col];
#pragma unroll
            for (int i = 0; i < 4; ++i) {
                const int rowl = wm + i * 16 + quad * 4;
#pragma unroll
                for (int r = 0; r < 4; ++r)
                    SA[(rowl + r) * LDT2 + col] = f2b(lrelu01(acc[i][j][r] + bv));
            }
        }
        __syncthreads();
    }
    // ---- stage 1: nf = lrelu(hmid x Wli^T + bli) -> NF global + SA (overwrite) ----
    {
        f32x4 acc[4][4] = {};
        for (int k0 = 0; k0 < 128; k0 += 32) {
#pragma unroll
            for (int h = 0; h < 2; ++h) {
                int ch = tid + h * 256;
                int row = ch >> 2, cp = ch & 3;
                *(float4*)&Ws[row * LDT + cp * 8] =
                    *(const float4*)(Wli + (size_t)row * 128 + k0 + cp * 8);
            }
            __syncthreads();
            frag8 af[4], bf[4];
#pragma unroll
            for (int i = 0; i < 4; ++i)
                af[i] = *(const frag8*)&SA[(wm + i * 16 + lrow) * LDT2 + k0 + quad * 8];
#pragma unroll
            for (int j = 0; j < 4; ++j)
                bf[j] = *(const frag8*)&Ws[(wn + j * 16 + lrow) * LDT + quad * 8];
#pragma unroll
            for (int i = 0; i < 4; ++i)
#pragma unroll
                for (int j = 0; j < 4; ++j)
                    acc[i][j] = __builtin_amdgcn_mfma_f32_16x16x32_bf16(af[i], bf[j], acc[i][j], 0, 0, 0);
            __syncthreads();
        }
#pragma unroll
        for (int j = 0; j < 4; ++j) {
            const int col = wn + j * 16 + lrow;
            float bv = bli[col];
#pragma unroll
            for (int i = 0; i < 4; ++i) {
                const int rowl = wm + i * 16 + quad * 4;
#pragma unroll
                for (int r = 0; r < 4; ++r) {
                    unsigned short h = f2b(lrelu01(acc[i][j][r] + bv));
                    NF[(size_t)(bn0 + rowl + r) * 128 + col] = h;
                    SA[(rowl + r) * LDT2 + col] = h;
                }
            }
        }
        __syncthreads();
    }
    // ---- stage 2: q = (nf x Wgc^T) * dinv -> Q ----
    {
        f32x4 acc[4][4] = {};
        for (int k0 = 0; k0 < 128; k0 += 32) {
#pragma unroll
            for (int h = 0; h < 2; ++h) {
                int ch = tid + h * 256;
                int row = ch >> 2, cp = ch & 3;
                *(float4*)&Ws[row * LDT + cp * 8] =
                    *(const float4*)(Wgc + (size_t)row * 128 + k0 + cp * 8);
            }
            __syncthreads();
            frag8 af[4], bf[4];
#pragma unroll
            for (int i = 0; i < 4; ++i)
                af[i] = *(const frag8*)&SA[(wm + i * 16 + lrow) * LDT2 + k0 + quad * 8];
#pragma unroll
            for (int j = 0; j < 4; ++j)
                bf[j] = *(const frag8*)&Ws[(wn + j * 16 + lrow) * LDT + quad * 8];
#pragma unroll
            for (int i = 0; i < 4; ++i)
#pragma unroll
                for (int j = 0; j < 4; ++j)
                    acc[i][j] = __builtin_amdgcn_mfma_f32_16x16x32_bf16(af[i], bf[j], acc[i][j], 0, 0, 0);
            __syncthreads();
        }
#pragma unroll
        for (int j = 0; j < 4; ++j) {
            const int col = wn + j * 16 + lrow;
#pragma unroll
            for (int i = 0; i < 4; ++i) {
                const int rowb = bn0 + wm + i * 16 + quad * 4;
#pragma unroll
                for (int r = 0; r < 4; ++r)
                    Q[(size_t)(rowb + r) * 128 + col] = f2b(acc[i][j][r] * dinv[rowb + r]);
            }
        }
    }
}

// out = c4 (from pooled) + xdot  — tiny
__global__ void k_out2(const float* __restrict__ xdot, const float* __restrict__ ow,
                       const float* __restrict__ ob, const float* __restrict__ pooled,
                       float* __restrict__ out, int n, float invn) {
    __shared__ float c4s[4];
    int tid = threadIdx.x;
    {
        int j = tid >> 6, lane = tid & 63;
        float s = 0.f;
        for (int c = lane; c < 256; c += 64) s += pooled[c] * invn * ow[j * 320 + c];
#pragma unroll
        for (int off = 32; off > 0; off >>= 1) s += __shfl_down(s, off);
        if (lane == 0) c4s[j] = s + ob[j];
    }
    __syncthreads();
    int node = blockIdx.x * 256 + tid;
    if (node >= n) return;
    float4 xd = *(const float4*)(xdot + (size_t)node * 4);
    *(float4*)(out + (size_t)node * 4) =
        make_float4(c4s[0] + xd.x, c4s[1] + xd.y, c4s[2] + xd.z, c4s[3] + xd.w);
}

// ================= launch =================
// Buffer lifetimes:
//   F1 [N,128]f32: z2 only
//   B1 [N,64] u16: h1 -> nf1
//   B2 [(N*128+128)]u16: A3F -> q1 (first N*64) -> q2.  The 128-entry row at
//       offset N*128 is zeroed in the prologue and never overwritten: shared
//       gather dummy row (idx 2N for CH=64 rows, idx N for CH=128 rows).
//   B3 [N,128]u16: hln1 -> nf2 (k_cligc rewrites its own rows in place)
//   H  [N,320]u16: xg cols 256.. (early), LN2 out cols 0..255 (late)
//   XD [N,4]f32:   per-node xg(dot)ow partial for the head

extern "C" void kernel_launch(void* const* d_in, const int* in_sizes, int n_in,
                              void* d_out, int out_size, void* d_ws, size_t ws_size,
                              hipStream_t stream) {
    const float* x   = (const float*)d_in[0];
    const int*   ei  = (const int*)d_in[1];
    const float* c1w = (const float*)d_in[2];  const float* c1b = (const float*)d_in[3];
    const float* c2w = (const float*)d_in[4];  const float* c2b = (const float*)d_in[5];
    const float* c3w = (const float*)d_in[6];  const float* c3b = (const float*)d_in[7];
    const float* f1w = (const float*)d_in[8];  const float* f1b = (const float*)d_in[9];
    const float* f2w = (const float*)d_in[10]; const float* f2bp = (const float*)d_in[11];
    const float* f3w = (const float*)d_in[12]; const float* f3b = (const float*)d_in[13];
    const float* cv1w = (const float*)d_in[14]; const float* cv1b = (const float*)d_in[15];
    const float* li1w = (const float*)d_in[16]; const float* li1b = (const float*)d_in[17];
    const float* gc1w = (const float*)d_in[18]; const float* gc1b = (const float*)d_in[19];
    const float* ln1g = (const float*)d_in[20]; const float* ln1b = (const float*)d_in[21];
    const float* cv2w = (const float*)d_in[22]; const float* cv2b = (const float*)d_in[23];
    const float* li2w = (const float*)d_in[24]; const float* li2b = (const float*)d_in[25];
    const float* gc2w = (const float*)d_in[26]; const float* gc2b = (const float*)d_in[27];
    const float* ln2g = (const float*)d_in[28]; const float* ln2b = (const float*)d_in[29];
    const float* cv3w = (const float*)d_in[30]; const float* cv3b = (const float*)d_in[31];
    const float* ow  = (const float*)d_in[32]; const float* ob  = (const float*)d_in[33];
    float* out = (float*)d_out;

    const int N = in_sizes[0] / 3;
    const int E = in_sizes[1] / 2;
    const int* srcI = ei;
    const int* dstI = ei + E;

    char* base = (char*)d_ws;
    size_t off = 0;
    auto take = [&](size_t bytes) -> char* {
        char* p = base + off;
        off = (off + bytes + 255) & ~(size_t)255;
        return p;
    };
    int*   deg    = (int*)  take((size_t)N * 4);
    float* sm     = (float*)take(8192 * 4);      // adjacent to deg -> single memset
    float* dinv   = (float*)take((size_t)N * 4);
    int*   startv = (int*)  take((size_t)N * 4);
    int*   rank   = (int*)  take((size_t)E * 4);
    int*   csr    = (int*)  take((size_t)E * 4);
    int*   bsum   = (int*)  take(512 * 4);
    unsigned short* WB = (unsigned short*)take(278528 * 2);
    unsigned short* H  = (unsigned short*)take((size_t)N * 320 * 2);
    float* F1 = (float*)take((size_t)N * 128 * 4);
    unsigned short* B1 = (unsigned short*)take((size_t)N * 64 * 2);
    unsigned short* B2 = (unsigned short*)take(((size_t)N * 128 + 128) * 2);
    unsigned short* B3 = (unsigned short*)take((size_t)N * 128 * 2);
    float* XD = (float*)take((size_t)N * 4 * 4);

    unsigned short* c2wb  = WB + 0;
    unsigned short* c3wf  = WB + 8192;   // fragment-order c3 weights (8 x 16384)
    unsigned short* li1wb = WB + 139264;
    unsigned short* gc1wb = WB + 143360;
    unsigned short* cv2wb = WB + 147456;
    unsigned short* li2wb = WB + 163840;
    unsigned short* gc2wb = WB + 180224;
    unsigned short* cv3wb = WB + 196608;

    float* sum2 = sm + 0;    float* ss2 = sm + 128;
    float* sum3 = sm + 256;  float* ss3 = sm + 1280;
    unsigned* maxk = (unsigned*)(sm + 2304);
    float* pooled = sm + 3328;
    unsigned* dmax = (unsigned*)(sm + 3584);   // 3584..3711
    unsigned* cnt1 = (unsigned*)(sm + 3712);
    unsigned* cnt2 = (unsigned*)(sm + 3713);
    float* T9  = sm + 3968;
    float* a1  = sm + 5120;   // 512 floats
    float* a2  = sm + 5760;   // 256 floats

    const float invn = 1.0f / (float)N;
    const dim3 blk(256);
    const unsigned GX = (unsigned)(N / 128);
    const unsigned NB = cdivu((unsigned)N, 256);
    const unsigned EB = cdivu((unsigned)E, 256);
    const unsigned WCB = cdivu(278528u, 256);
    const unsigned PB = cdivu((unsigned)N * 16, 256);
    const unsigned NZ = 8 * GX;

    // merged memset: deg (padded to 256B) + sm prefix (stats + spin counters)
    size_t degpad = ((size_t)N * 4 + 255) & ~(size_t)255;
    hipMemsetAsync(deg, 0, degpad + 3720 * 4, stream);
    // shared 256B zero row at B2 + N*128 entries (gather dummy for both glns)
    hipMemsetAsync(B2 + (size_t)N * 128, 0, 256, stream);

    // FK1: degree/rank atomics || weight pack || tnet-c1
    FK1<<<EB + WCB + NB, blk, 0, stream>>>(dstI, deg, rank, E, (int)EB,
                                           c2w, c3w, li1w, gc1w, cv2w, li2w, gc2w, cv3w,
                                           WB, (int)WCB, x, c1w, c1b, B1, N);
    // FK2: z2 GEMM (stats) || local scan + dinv
    FK2<<<GX + NB, blk, 0, stream>>>(B1, 64, 64, c2wb, c2b, F1, 128,
                                     sum2, ss2, dmax, (int)GX, deg, startv, bsum, dinv, N);
    // FK3: pre-BN repack || block-sum scan
    FK3<<<PB + 1, blk, 0, stream>>>(F1, sum2, ss2, B2, N * 16, invn, (int)PB, bsum, (int)NB);
    // FK4: z3 stats GEMM ||| CSR fill, parity-interleaved, single call site per body
    FK4<<<NZ + EB, blk, 0, stream>>>(B2, c3wf, c3b, sum3, ss3, maxk, (int)NZ, (int)EB,
                                     srcI, dstI, rank, startv, bsum, csr, E);
    // TNet tail: fc1+fc2+fc3 fused via 32-block spin barriers
    k_tnet<<<32, blk, 0, stream>>>(sum3, ss3, maxk, f1w, f1b, f2w, f2bp, f3w, f3b,
                                   a1, a2, T9, cnt1, cnt2, invn);
    // xg + xdot
    k_xg2<<<NB, blk, 0, stream>>>(x, T9, cv1w, cv1b, ow, H + 256, XD, N);

    // ---- GCN block 1 (C=64) ----
    k_ligc<64><<<GX, blk, 0, stream>>>(H + 256, 320, 64, li1wb, li1b, gc1wb, dinv, B1, 64, B2, 64);
    k_gln<64><<<cdivu((unsigned)N, 4), blk, 0, stream>>>(
        startv, bsum, deg, csr, B2, B1, dinv, gc1b, ln1g, ln1b, B3, 128, N, 2 * N);

    // ---- GCN block 2 (C=128): conv2+li2+gc2 fused ----
    k_cligc<<<GX, blk, 0, stream>>>(B3, cv2wb, cv2b, li2wb, li2b, gc2wb, dinv, B3, B2);
    k_gln<128><<<cdivu((unsigned)N, 4), blk, 0, stream>>>(
        startv, bsum, deg, csr, B2, B3, dinv, gc2b, ln2g, ln2b, H, 320, N, N);

    // ---- conv3 (K=320 -> 256), SWAP grid so both col-blocks of a row-tile are adjacent ----
    k_mgemm<128, (MF_BIAS | MF_LRELU | MF_COLSUM), 1><<<dim3(2, GX), blk, 0, stream>>>(
        H, 320, 320, cv3wb, cv3b, nullptr, nullptr, 0, nullptr, pooled, nullptr, nullptr);

    // ---- head ----
    k_out2<<<NB, blk, 0, stream>>>(XD, ow, ob, pooled, out, N, invn);
}

// Round 7
// 488.160 us; speedup vs baseline: 1.2922x; 1.0590x over previous
//
#include <hip/hip_runtime.h>
#include <cstddef>

#define EPSV 1e-5f

typedef __attribute__((ext_vector_type(8))) short frag8;   // 8 bf16 (4 VGPRs)
typedef __attribute__((ext_vector_type(4))) float f32x4;   // MFMA acc

__device__ __forceinline__ float lrelu01(float v) { return v > 0.f ? v : 0.01f * v; }
__device__ __forceinline__ void atomAddF(float* p, float v) { unsafeAtomicAdd(p, v); }
__device__ __forceinline__ unsigned fkey(float f) {
    unsigned u = __float_as_uint(f);
    return (u & 0x80000000u) ? ~u : (u | 0x80000000u);
}
__device__ __forceinline__ unsigned short f2b(float f) {  // RNE float->bf16
    unsigned u = __float_as_uint(f);
    unsigned r = u + 0x7fffu + ((u >> 16) & 1u);
    return (unsigned short)(r >> 16);
}
__device__ __forceinline__ float b2f(unsigned short h) {
    return __uint_as_float(((unsigned)h) << 16);
}
__device__ __forceinline__ float blo(unsigned u) { return __uint_as_float(u << 16); }
__device__ __forceinline__ float bhi(unsigned u) { return __uint_as_float(u & 0xffff0000u); }

static inline unsigned cdivu(unsigned a, unsigned b) { return (a + b - 1) / b; }

// device-scope spin barrier for a small, fully-co-resident grid.
// cnt lives in memset-zeroed workspace; replay-after-completion is idempotent.
__device__ __forceinline__ void gbar(unsigned* cnt, unsigned target) {
    __syncthreads();
    if (threadIdx.x == 0) {
        __threadfence();
        atomicAdd(cnt, 1u);
        while (atomicAdd(cnt, 0u) < target) { }
        __threadfence();
    }
    __syncthreads();
}

// ================= graph prep bodies =================

__device__ void degrank_body(int bid, const int* __restrict__ dst, int* __restrict__ deg,
                             int* __restrict__ rank, int E) {
    int e = bid * 256 + threadIdx.x;
    if (e < E) rank[e] = atomicAdd(&deg[dst[e]], 1);
}

__device__ void scan_local_body(int bid, const int* __restrict__ deg, int* __restrict__ startv,
                                int* __restrict__ bsum, float* __restrict__ dinv, int n) {
    __shared__ int t0[256];
    int tid = threadIdx.x;
    int i = bid * 256 + tid;
    int v = (i < n) ? deg[i] : 0;
    if (i < n) dinv[i] = rsqrtf((float)(v + 1));  // +1 self loop
    t0[tid] = v;
    __syncthreads();
    for (int o = 1; o < 256; o <<= 1) {
        int add = (tid >= o) ? t0[tid - o] : 0;
        __syncthreads();
        t0[tid] += add;
        __syncthreads();
    }
    if (i < n) startv[i] = t0[tid] - v;
    if (tid == 255) bsum[bid] = t0[255];
}

// 256-thread scan over up to 512 block sums (ping-pong Hillis-Steele)
__device__ void scan_bsum_body(int* __restrict__ bsum, int nb) {
    __shared__ int t0[512];
    __shared__ int t1[512];
    int tid = threadIdx.x;
    int v0 = (tid < nb) ? bsum[tid] : 0;
    int v1 = (tid + 256 < nb) ? bsum[tid + 256] : 0;
    t0[tid] = v0; t0[tid + 256] = v1;
    __syncthreads();
    int* a = t0; int* b = t1;
    for (int o = 1; o < 512; o <<= 1) {
        b[tid]       = a[tid]       + ((tid >= o)       ? a[tid - o]       : 0);
        b[tid + 256] = a[tid + 256] + ((tid + 256 >= o) ? a[tid + 256 - o] : 0);
        __syncthreads();
        int* t = a; a = b; b = t;
    }
    if (tid < nb) bsum[tid] = a[tid] - v0;
    if (tid + 256 < nb) bsum[tid + 256] = a[tid + 256] - v1;
}

// fill using local startv + block-prefix bsum (no scan_add pass needed)
__device__ void fill_body(int bid, const int* __restrict__ src, const int* __restrict__ dst,
                          const int* __restrict__ rank, const int* __restrict__ startv,
                          const int* __restrict__ bsum, int* __restrict__ csr, int E) {
    int e = bid * 256 + threadIdx.x;
    if (e < E) {
        int d = dst[e];
        csr[startv[d] + bsum[d >> 8] + rank[e]] = src[e];
    }
}

// ================= small bodies =================

__device__ void wconv_body(int bid, const float* __restrict__ s0, const float* __restrict__ s1,
                           const float* __restrict__ s2, const float* __restrict__ s3,
                           const float* __restrict__ s4, const float* __restrict__ s5,
                           const float* __restrict__ s6, const float* __restrict__ s7,
                           unsigned short* __restrict__ dst) {
    int t = bid * 256 + threadIdx.x;
    if (t >= 278528) return;
    const float* srcs[8] = {s0, s1, s2, s3, s4, s5, s6, s7};
    const int off[9] = {0, 8192, 139264, 143360, 147456, 163840, 180224, 196608, 278528};
    int seg = 0;
    while (t >= off[seg + 1]) ++seg;
    unsigned short v = f2b(srcs[seg][t - off[seg]]);
    if (seg == 1) {
        int li = t - 8192;
        int rch = li >> 7, k = li & 127;
        int cb = rch >> 7, r = rch & 127;
        int flat = ((r >> 4) * 4 + (k >> 5)) * 64 + ((k >> 3) & 3) * 16 + (r & 15);
        dst[8192 + cb * 16384 + flat * 8 + (k & 7)] = v;
    } else {
        dst[t] = v;
    }
}

__device__ void h1_body(int bid, const float* __restrict__ x, const float* __restrict__ w,
                        const float* __restrict__ b, unsigned short* __restrict__ h1, int n) {
    int node = bid * 256 + threadIdx.x;
    if (node >= n) return;
    float x0 = x[node * 3], x1 = x[node * 3 + 1], x2 = x[node * 3 + 2];
    unsigned short* o = h1 + (size_t)node * 64;
#pragma unroll
    for (int cp = 0; cp < 8; ++cp) {
        unsigned short tmp[8];
#pragma unroll
        for (int t = 0; t < 8; ++t) {
            int c = cp * 8 + t;
            float v = x0 * w[c * 3] + x1 * w[c * 3 + 1] + x2 * w[c * 3 + 2] + b[c];
            tmp[t] = f2b(fmaxf(v, 0.f));
        }
        *(float4*)(o + cp * 8) = *(float4*)tmp;
    }
}

__device__ void prebn_body(int bid, const float* __restrict__ z, const float* __restrict__ sum2,
                           const float* __restrict__ ss2, unsigned short* __restrict__ a3f,
                           int n16, float invn) {
    int t = bid * 256 + threadIdx.x;
    if (t >= n16) return;
    int row = t >> 4, cp = t & 15;
    int c = cp * 8;
    const float* src = z + (size_t)row * 128 + c;
    float4 v0 = *(const float4*)src;
    float4 v1 = *(const float4*)(src + 4);
    float vv[8] = {v0.x, v0.y, v0.z, v0.w, v1.x, v1.y, v1.z, v1.w};
    unsigned short o[8];
#pragma unroll
    for (int i = 0; i < 8; ++i) {
        float m = sum2[c + i] * invn;
        float var = ss2[c + i] * invn - m * m;
        o[i] = f2b(fmaxf((vv[i] - m) * rsqrtf(var + EPSV), 0.f));
    }
    int tile = row >> 7, r = row & 127;
    int flat = ((r >> 4) * 4 + (cp >> 2)) * 64 + (cp & 3) * 16 + (r & 15);
    *(float4*)(a3f + (size_t)tile * 16384 + flat * 8) = *(float4*)o;
}

// ================= MFMA GEMM body (generic, BK=32) =================
enum { MF_BIAS = 1, MF_LRELU = 2, MF_DINV = 4, MF_STOREF = 8, MF_STOREB = 16,
       MF_STATS = 32, MF_COLSUM = 64 };

template <int BN, int MODE>
__device__ void mgemm_body(int bx, int by,
                           const unsigned short* __restrict__ A, int lda, int K,
                           const unsigned short* __restrict__ W,  // [C][K]
                           const float* __restrict__ bias,
                           float* __restrict__ OutF, unsigned short* __restrict__ OutB, int ldo,
                           const float* __restrict__ dinv,
                           float* __restrict__ sum_o, float* __restrict__ ss_o,
                           unsigned* __restrict__ maxk_o) {
    constexpr int BM = 128;
    constexpr int LDT = 40;
    __shared__ unsigned short As[BM * LDT];
    __shared__ unsigned short Ws[BN * LDT];
    __shared__ float redS[2 * 128];
    __shared__ unsigned redM[128];

    const int tid = threadIdx.x;
    const int wid = tid >> 6, lane = tid & 63;
    const int quad = lane >> 4, lrow = lane & 15;
    const int bn0 = bx * BM;
    const int bc0 = by * BN;

    constexpr int NI = (BN == 128) ? 4 : 2;
    constexpr int NJ = 4;
    const int wm = (BN == 128) ? (wid & 1) * 64 : wid * 32;
    const int wn = (BN == 128) ? (wid >> 1) * 64 : 0;

    if (MODE & (MF_STATS | MF_COLSUM)) {
        for (int c = tid; c < BN; c += 256) {
            redS[c] = 0.f; redS[128 + c] = 0.f; redM[c] = 0u;
        }
    }

    f32x4 acc[NI][NJ] = {};

    for (int k0 = 0; k0 < K; k0 += 32) {
#pragma unroll
        for (int h = 0; h < 2; ++h) {
            int ch = tid + h * 256;
            int row = ch >> 2, cp = ch & 3;
            const unsigned short* src = A + (size_t)(bn0 + row) * lda + k0 + cp * 8;
            *(float4*)&As[row * LDT + cp * 8] = *(const float4*)src;
        }
#pragma unroll
        for (int h = 0; h < BN / 64; ++h) {
            int ch = tid + h * 256;
            int row = ch >> 2, cp = ch & 3;
            const unsigned short* src = W + (size_t)(bc0 + row) * K + k0 + cp * 8;
            *(float4*)&Ws[row * LDT + cp * 8] = *(const float4*)src;
        }
        __syncthreads();
        frag8 af[NI], bf[NJ];
#pragma unroll
        for (int i = 0; i < NI; ++i)
            af[i] = *(const frag8*)&As[(wm + i * 16 + lrow) * LDT + quad * 8];
#pragma unroll
        for (int j = 0; j < NJ; ++j)
            bf[j] = *(const frag8*)&Ws[(wn + j * 16 + lrow) * LDT + quad * 8];
#pragma unroll
        for (int i = 0; i < NI; ++i)
#pragma unroll
            for (int j = 0; j < NJ; ++j)
                acc[i][j] = __builtin_amdgcn_mfma_f32_16x16x32_bf16(af[i], bf[j], acc[i][j], 0, 0, 0);
        __syncthreads();
    }

#pragma unroll
    for (int j = 0; j < NJ; ++j) {
        const int col = bc0 + wn + j * 16 + lrow;
        float bv = (MODE & MF_BIAS) ? bias[col] : 0.f;
        float s = 0.f, q = 0.f, m = -3.4e38f;
#pragma unroll
        for (int i = 0; i < NI; ++i) {
            const int rowb = bn0 + wm + i * 16 + quad * 4;
#pragma unroll
            for (int r = 0; r < 4; ++r) {
                float t = acc[i][j][r] + bv;
                if (MODE & MF_LRELU) t = lrelu01(t);
                if (MODE & MF_DINV) t *= dinv[rowb + r];
                if (MODE & MF_STOREF) OutF[(size_t)(rowb + r) * ldo + col] = t;
                if (MODE & MF_STOREB) OutB[(size_t)(rowb + r) * ldo + col] = f2b(t);
                s += t; q += t * t; m = fmaxf(m, t);
            }
        }
        if (MODE & (MF_STATS | MF_COLSUM)) {
            s += __shfl_xor(s, 16); s += __shfl_xor(s, 32);
            if (MODE & MF_STATS) {
                q += __shfl_xor(q, 16); q += __shfl_xor(q, 32);
                m = fmaxf(m, __shfl_xor(m, 16)); m = fmaxf(m, __shfl_xor(m, 32));
            }
            if (quad == 0) {
                int lc = wn + j * 16 + lrow;
                atomicAdd(&redS[lc], s);
                if (MODE & MF_STATS) {
                    atomicAdd(&redS[128 + lc], q);
                    atomicMax(&redM[lc], fkey(m));
                }
            }
        }
    }
    if (MODE & (MF_STATS | MF_COLSUM)) {
        __syncthreads();
        for (int c = tid; c < BN; c += 256) {
            atomAddF(&sum_o[bc0 + c], redS[c]);
            if (MODE & MF_STATS) {
                atomAddF(&ss_o[bc0 + c], redS[128 + c]);
                atomicMax(&maxk_o[bc0 + c], redM[c]);
            }
        }
    }
}

// standalone GEMM wrapper; SWAP=1 maps row-tile to blockIdx.y so the two
// column-blocks of one row-tile are dispatch-adjacent (A tile L2-hit).
template <int BN, int MODE, int SWAP>
__launch_bounds__(256)
__global__ void k_mgemm(const unsigned short* __restrict__ A, int lda, int K,
                        const unsigned short* __restrict__ W,
                        const float* __restrict__ bias,
                        float* __restrict__ OutF, unsigned short* __restrict__ OutB, int ldo,
                        const float* __restrict__ dinv,
                        float* __restrict__ sum_o, float* __restrict__ ss_o,
                        unsigned* __restrict__ maxk_o) {
    int bx = SWAP ? blockIdx.y : blockIdx.x;
    int by = SWAP ? blockIdx.x : blockIdx.y;
    mgemm_body<BN, MODE>(bx, by, A, lda, K, W, bias, OutF, OutB, ldo, dinv, sum_o, ss_o, maxk_o);
}

// ================= z3 stats GEMM: no LDS, no barrier =================
// XCD-swizzled mapping (round-0 verified): dispatch round-robins blocks across
// the 8 XCDs, so bid&7 = XCD. w = (bid&7)*ntiles + bid>>3 gives each XCD a
// CONTIGUOUS w-range -> the 8 cb-variants sharing one 32KB A tile land on ONE
// XCD -> A tile stays hot in that XCD's L2.
__device__ void z3_body(int bid,
                        const unsigned short* __restrict__ AF,
                        const unsigned short* __restrict__ WF,
                        const float* __restrict__ bias,
                        float* __restrict__ sum_o, float* __restrict__ ss_o,
                        unsigned* __restrict__ maxk_o, int ntiles) {
    const int tid = threadIdx.x;
    const int wid = tid >> 6, lane = tid & 63;
    const int quad = lane >> 4, lrow = lane & 15;

    int w = (bid & 7) * ntiles + (bid >> 3);
    const int tile = w >> 3;
    const int cb = w & 7;
    const unsigned short* At = AF + (size_t)tile * 16384;
    const unsigned short* Wt = WF + (size_t)cb * 16384;

    const int ar = (wid & 1) * 4;
    const int wc = (wid >> 1) * 4;
    f32x4 acc[4][4] = {};
#pragma unroll
    for (int kc = 0; kc < 4; ++kc) {
        frag8 af[4], bf[4];
#pragma unroll
        for (int i = 0; i < 4; ++i)
            af[i] = *(const frag8*)&At[(((ar + i) * 4 + kc) * 64 + lane) * 8];
#pragma unroll
        for (int j = 0; j < 4; ++j)
            bf[j] = *(const frag8*)&Wt[(((wc + j) * 4 + kc) * 64 + lane) * 8];
#pragma unroll
        for (int i = 0; i < 4; ++i)
#pragma unroll
            for (int j = 0; j < 4; ++j)
                acc[i][j] = __builtin_amdgcn_mfma_f32_16x16x32_bf16(af[i], bf[j], acc[i][j], 0, 0, 0);
    }

#pragma unroll
    for (int j = 0; j < 4; ++j) {
        int c = cb * 128 + (wc + j) * 16 + lrow;
        float bv = bias[c];
        float s = 0.f, q = 0.f, m = -3.4e38f;
#pragma unroll
        for (int i = 0; i < 4; ++i)
#pragma unroll
            for (int r = 0; r < 4; ++r) {
                float t = acc[i][j][r] + bv;
                s += t; q += t * t; m = fmaxf(m, t);
            }
        s += __shfl_xor(s, 16); s += __shfl_xor(s, 32);
        q += __shfl_xor(q, 16); q += __shfl_xor(q, 32);
        m = fmaxf(m, __shfl_xor(m, 16)); m = fmaxf(m, __shfl_xor(m, 32));
        if (quad == 0) {
            atomAddF(&sum_o[c], s);
            atomAddF(&ss_o[c], q);
            atomicMax(&maxk_o[c], fkey(m));
        }
    }
}

// ================= fat kernels =================

__launch_bounds__(256)
__global__ void FK1(const int* __restrict__ dst, int* __restrict__ deg, int* __restrict__ rank,
                    int E, int EB,
                    const float* s0, const float* s1, const float* s2, const float* s3,
                    const float* s4, const float* s5, const float* s6, const float* s7,
                    unsigned short* __restrict__ WB, int WCB,
                    const float* __restrict__ x, const float* __restrict__ c1w,
                    const float* __restrict__ c1b, unsigned short* __restrict__ B1, int n) {
    int b = blockIdx.x;
    if (b < EB) { degrank_body(b, dst, deg, rank, E); return; }
    b -= EB;
    if (b < WCB) { wconv_body(b, s0, s1, s2, s3, s4, s5, s6, s7, WB); return; }
    b -= WCB;
    h1_body(b, x, c1w, c1b, B1, n);
}

__launch_bounds__(256)
__global__ void FK2(const unsigned short* __restrict__ A, int lda, int K,
                    const unsigned short* __restrict__ W, const float* __restrict__ bias,
                    float* __restrict__ OutF, int ldo,
                    float* __restrict__ sum_o, float* __restrict__ ss_o,
                    unsigned* __restrict__ maxk_o, int GXz,
                    const int* __restrict__ deg, int* __restrict__ startv,
                    int* __restrict__ bsum, float* __restrict__ dinvv, int n) {
    if ((int)blockIdx.x < GXz)
        mgemm_body<128, (MF_BIAS | MF_STOREF | MF_STATS)>(
            blockIdx.x, 0, A, lda, K, W, bias, OutF, nullptr, ldo, nullptr, sum_o, ss_o, maxk_o);
    else
        scan_local_body(blockIdx.x - GXz, deg, startv, bsum, dinvv, n);
}

__launch_bounds__(256)
__global__ void FK3(const float* __restrict__ z, const float* __restrict__ sum2,
                    const float* __restrict__ ss2, unsigned short* __restrict__ a3f,
                    int n16, float invn, int PB, int* __restrict__ bsum, int nb) {
    if ((int)blockIdx.x < PB) prebn_body(blockIdx.x, z, sum2, ss2, a3f, n16, invn);
    else scan_bsum_body(bsum, nb);
}

// FK4: z3 stats GEMM then CSR fill, APPENDED mapping (phase-serialized in-kernel).
// Round-6 lesson: parity-interleaving z3 with fill's random scatter thrashes the
// per-XCD L2 (FETCH 20->48 MB, dur 74->100 us). Serial phases within one kernel
// keep the caches phase-coherent. Single call site per body (round-5 lesson:
// duplicated call sites blew regalloc to 144 VGPR).
__launch_bounds__(256)
__global__ void FK4(const unsigned short* __restrict__ AF, const unsigned short* __restrict__ WF,
                    const float* __restrict__ bias,
                    float* __restrict__ sum_o, float* __restrict__ ss_o,
                    unsigned* __restrict__ maxk_o, int NZ, int ntiles,
                    const int* __restrict__ src, const int* __restrict__ dst,
                    const int* __restrict__ rank, const int* __restrict__ startv,
                    const int* __restrict__ bsum, int* __restrict__ csr, int E) {
    int b = blockIdx.x;
    bool dofill = (b >= NZ);
    int idx = dofill ? (b - NZ) : b;
    if (dofill) fill_body(idx, src, dst, rank, startv, bsum, csr, E);
    else        z3_body(idx, AF, WF, bias, sum_o, ss_o, maxk_o, ntiles);
}

// k_tnet: fc1 + fc2 + fc3 in ONE 32-block kernel with device spin barriers.
// 32 blocks trivially co-resident; counters zeroed by the per-iteration memset.
__launch_bounds__(256)
__global__ void k_tnet(const float* __restrict__ sum3, const float* __restrict__ ss3,
                       const unsigned* __restrict__ maxk,
                       const float* __restrict__ f1w, const float* __restrict__ f1b,
                       const float* __restrict__ f2w, const float* __restrict__ f2bias,
                       const float* __restrict__ f3w, const float* __restrict__ f3b,
                       float* __restrict__ a1, float* __restrict__ a2,
                       float* __restrict__ T9,
                       unsigned* __restrict__ cnt1, unsigned* __restrict__ cnt2, float invn) {
    __shared__ float g[1024];
    __shared__ float a1s[512];
    int tid = threadIdx.x;
    int bid = blockIdx.x;
    // ---- g = relu(bn(maxpool)) ----
    for (int c = tid; c < 1024; c += 256) {
        float m = sum3[c] * invn;
        float var = ss3[c] * invn - m * m;
        unsigned k = maxk[c];
        unsigned u = (k & 0x80000000u) ? (k & 0x7FFFFFFFu) : ~k;
        g[c] = fmaxf((__uint_as_float(u) - m) * rsqrtf(var + EPSV), 0.f);
    }
    __syncthreads();
    // ---- fc1: 16 rows/block, 16 lanes/row ----
    {
        int row = bid * 16 + (tid >> 4);
        int part = tid & 15;
        const float* w = f1w + (size_t)row * 1024 + part * 64;
        const float* gg = g + part * 64;
        float s = 0.f;
#pragma unroll 4
        for (int k = 0; k < 64; k += 4) {
            float4 wv = *(const float4*)(w + k);
            s = fmaf(wv.x, gg[k], s);
            s = fmaf(wv.y, gg[k + 1], s);
            s = fmaf(wv.z, gg[k + 2], s);
            s = fmaf(wv.w, gg[k + 3], s);
        }
        s += __shfl_xor(s, 1); s += __shfl_xor(s, 2);
        s += __shfl_xor(s, 4); s += __shfl_xor(s, 8);
        if (part == 0) a1[row] = fmaxf(s + f1b[row], 0.f);
    }
    gbar(cnt1, 32);
    // ---- fc2: 8 rows/block, 32 lanes/row ----
    a1s[tid] = a1[tid];
    a1s[tid + 256] = a1[tid + 256];
    __syncthreads();
    {
        int row = bid * 8 + (tid >> 5);
        int part = tid & 31;
        const float* w = f2w + (size_t)row * 512 + part * 16;
        const float* aa = a1s + part * 16;
        float s = 0.f;
#pragma unroll
        for (int k = 0; k < 16; k += 4) {
            float4 wv = *(const float4*)(w + k);
            s = fmaf(wv.x, aa[k], s);
            s = fmaf(wv.y, aa[k + 1], s);
            s = fmaf(wv.z, aa[k + 2], s);
            s = fmaf(wv.w, aa[k + 3], s);
        }
        s += __shfl_xor(s, 1); s += __shfl_xor(s, 2); s += __shfl_xor(s, 4);
        s += __shfl_xor(s, 8); s += __shfl_xor(s, 16);
        if (part == 0) a2[row] = fmaxf(s + f2bias[row], 0.f);
    }
    gbar(cnt2, 32);
    // ---- fc3 (block 0): 9 rows, 16 lanes/row ----
    if (bid == 0 && tid < 144) {
        int r = tid >> 4, kk = (tid & 15) * 16;
        const float* wr = f3w + r * 256 + kk;
        float s = 0.f;
#pragma unroll
        for (int k = 0; k < 16; ++k) s = fmaf(wr[k], a2[kk + k], s);
        s += __shfl_xor(s, 1); s += __shfl_xor(s, 2);
        s += __shfl_xor(s, 4); s += __shfl_xor(s, 8);
        if ((tid & 15) == 0) {
            s += f3b[r];
            if (r == 0 || r == 4 || r == 8) s += 1.f;
            T9[r] = s;
        }
    }
}

// ================= fused gather + LN =================
// nd = dummy row index (points at the shared 256B zero row at B2 + N*128 entries:
// nd = 2N when q rows are 64ch, nd = N when 128ch).
template <int CH>
__launch_bounds__(256)
__global__ void k_gln(const int* __restrict__ startv, const int* __restrict__ bsum,
                      const int* __restrict__ degv,
                      const int* __restrict__ csr, const unsigned short* __restrict__ q,
                      const unsigned short* __restrict__ nf, const float* __restrict__ dinv,
                      const float* __restrict__ gcn_b, const float* __restrict__ lng,
                      const float* __restrict__ lnb, unsigned short* __restrict__ outp,
                      int ldo, int n, int nd) {
    constexpr int GRP = (CH == 64) ? 8 : 4;   // rows in flight per load instr
    constexpr int PL  = 64 / GRP;             // lanes per row slice
    constexpr int TT  = 16 / GRP;             // load instrs per 16-edge chunk
    constexpr int CPL = CH / PL;              // = 8 channels per lane
    const int wv = threadIdx.x >> 6, lane = threadIdx.x & 63;
    const int g = lane / PL, p = lane & (PL - 1);
    int node = blockIdx.x * 4 + wv;
    if (node >= n) return;

    const unsigned short* qp = q + (size_t)p * CPL;

    float acc[CPL];
    {
        uint4 v = *(const uint4*)(qp + (size_t)node * CH);
        unsigned sv[4] = {v.x, v.y, v.z, v.w};
        if (g == 0) {
#pragma unroll
            for (int d = 0; d < 4; ++d) { acc[2 * d] = blo(sv[d]); acc[2 * d + 1] = bhi(sv[d]); }
        } else {
#pragma unroll
            for (int k = 0; k < CPL; ++k) acc[k] = 0.f;
        }
    }

    int s0 = startv[node] + bsum[node >> 8], cnt = degv[node];
    const int* cs = csr + s0;
    int sidx[TT];
#pragma unroll
    for (int t = 0; t < TT; ++t) { int j = t * GRP + g; sidx[t] = (j < cnt) ? cs[j] : nd; }
    for (int j0 = 0; j0 < cnt; j0 += 16) {
        uint4 buf[TT];
#pragma unroll
        for (int t = 0; t < TT; ++t)
            buf[t] = *(const uint4*)(qp + (size_t)(unsigned)sidx[t] * CH);
#pragma unroll
        for (int t = 0; t < TT; ++t) {
            int j = j0 + 16 + t * GRP + g;
            sidx[t] = (j < cnt) ? cs[j] : nd;
        }
#pragma unroll
        for (int t = 0; t < TT; ++t) {
            unsigned bw[4] = {buf[t].x, buf[t].y, buf[t].z, buf[t].w};
#pragma unroll
            for (int d = 0; d < 4; ++d) {
                acc[2 * d] += blo(bw[d]);
                acc[2 * d + 1] += bhi(bw[d]);
            }
        }
    }

#pragma unroll
    for (int k = 0; k < CPL; ++k) {
#pragma unroll
        for (int off = PL; off < 64; off <<= 1) acc[k] += __shfl_xor(acc[k], off);
    }

    float di = dinv[node];
    float nv[CPL], bv[CPL];
    {
        uint4 v = *(const uint4*)(nf + (size_t)node * CH + p * CPL);
        unsigned sv[4] = {v.x, v.y, v.z, v.w};
#pragma unroll
        for (int d = 0; d < 4; ++d) { nv[2 * d] = blo(sv[d]); nv[2 * d + 1] = bhi(sv[d]); }
    }
    const float* gb = gcn_b + p * CPL;
#pragma unroll
    for (int k = 0; k < CPL; ++k) bv[k] = lrelu01(di * acc[k] + gb[k]);

    float s = 0.f, ss = 0.f;
#pragma unroll
    for (int k = 0; k < CPL; ++k) { s += nv[k] + bv[k]; ss += nv[k] * nv[k] + bv[k] * bv[k]; }
#pragma unroll
    for (int off = 32; off > 0; off >>= 1) { s += __shfl_xor(s, off); ss += __shfl_xor(ss, off); }
    const float inv = 1.f / (float)(GRP * 2 * CH);  // GRP-way replication * 2*CH channels
    float mu = s * inv;
    float var = ss * inv - mu * mu;
    float rsg = rsqrtf(var + EPSV);

    unsigned short* orow = outp + (size_t)node * ldo;
    if (g == 0) {
        unsigned short tmp[CPL];
        const float* lg = lng + p * CPL; const float* lb = lnb + p * CPL;
#pragma unroll
        for (int k = 0; k < CPL; ++k) tmp[k] = f2b((nv[k] - mu) * rsg * lg[k] + lb[k]);
        *(uint4*)(orow + p * CPL) = *(uint4*)tmp;
    } else if (g == 1) {
        unsigned short tmp[CPL];
        const float* lg = lng + CH + p * CPL; const float* lb = lnb + CH + p * CPL;
#pragma unroll
        for (int k = 0; k < CPL; ++k) tmp[k] = f2b((bv[k] - mu) * rsg * lg[k] + lb[k]);
        *(uint4*)(orow + CH + p * CPL) = *(uint4*)tmp;
    }
}

// ================= remaining standalone kernels =================

// xg from T9; also emits xdot[node] = xg_row(dot)ow[:,256:320]
__launch_bounds__(256)
__global__ void k_xg2(const float* __restrict__ x, const float* __restrict__ T9,
                      const float* __restrict__ w, const float* __restrict__ b,
                      const float* __restrict__ ow,
                      unsigned short* __restrict__ xg, float* __restrict__ xdot, int n) {
    __shared__ float owS[256];
    __shared__ float T9s[9];
    int tid = threadIdx.x;
    owS[tid] = ow[(tid >> 6) * 320 + 256 + (tid & 63)];
    if (tid < 9) T9s[tid] = T9[tid];
    __syncthreads();
    int node = blockIdx.x * 256 + tid;
    if (node >= n) return;
    float x0 = x[node * 3], x1 = x[node * 3 + 1], x2 = x[node * 3 + 2];
    float h0 = x0 * T9s[0] + x1 * T9s[3] + x2 * T9s[6];
    float h1 = x0 * T9s[1] + x1 * T9s[4] + x2 * T9s[7];
    float h2 = x0 * T9s[2] + x1 * T9s[5] + x2 * T9s[8];
    unsigned short* o = xg + (size_t)node * 320;
    float d0 = 0.f, d1 = 0.f, d2 = 0.f, d3 = 0.f;
#pragma unroll
    for (int cp = 0; cp < 8; ++cp) {
        unsigned short tmp[8];
#pragma unroll
        for (int t = 0; t < 8; ++t) {
            int c = cp * 8 + t;
            float v = lrelu01(h0 * w[c * 3] + h1 * w[c * 3 + 1] + h2 * w[c * 3 + 2] + b[c]);
            tmp[t] = f2b(v);
            d0 = fmaf(v, owS[c], d0);
            d1 = fmaf(v, owS[64 + c], d1);
            d2 = fmaf(v, owS[128 + c], d2);
            d3 = fmaf(v, owS[192 + c], d3);
        }
        *(float4*)(o + cp * 8) = *(float4*)tmp;
    }
    *(float4*)(xdot + (size_t)node * 4) = make_float4(d0, d1, d2, d3);
}

// ---------------- fused li+gc (block 1, BN=64) ----------------
template <int BN>
__launch_bounds__(256)
__global__ void k_ligc(const unsigned short* __restrict__ A, int lda, int K,
                       const unsigned short* __restrict__ Wli, const float* __restrict__ bli,
                       const unsigned short* __restrict__ Wgc, const float* __restrict__ dinv,
                       unsigned short* __restrict__ NF, int ldnf,
                       unsigned short* __restrict__ Q, int ldq) {
    constexpr int BM = 128;
    constexpr int LDT = 40;
    constexpr int LDT2 = BN + 8;
    __shared__ unsigned short SA[BM * LDT2];
    __shared__ unsigned short Ws[BN * LDT];
    __shared__ unsigned short As[BM * LDT];

    const int tid = threadIdx.x;
    const int wid = tid >> 6, lane = tid & 63;
    const int quad = lane >> 4, lrow = lane & 15;
    const int bn0 = blockIdx.x * BM;
    constexpr int NI = (BN == 128) ? 4 : 2;
    constexpr int NJ = 4;
    const int wm = (BN == 128) ? (wid & 1) * 64 : wid * 32;
    const int wn = (BN == 128) ? (wid >> 1) * 64 : 0;

    // ---- stage 1: nf = lrelu(A x Wli^T + bli) -> NF global + SA ----
    {
        f32x4 acc[NI][NJ] = {};
        for (int k0 = 0; k0 < K; k0 += 32) {
#pragma unroll
            for (int h = 0; h < 2; ++h) {
                int ch = tid + h * 256;
                int row = ch >> 2, cp = ch & 3;
                *(float4*)&As[row * LDT + cp * 8] =
                    *(const float4*)(A + (size_t)(bn0 + row) * lda + k0 + cp * 8);
            }
#pragma unroll
            for (int h = 0; h < BN / 64; ++h) {
                int ch = tid + h * 256;
                int row = ch >> 2, cp = ch & 3;
                *(float4*)&Ws[row * LDT + cp * 8] =
                    *(const float4*)(Wli + (size_t)row * K + k0 + cp * 8);
            }
            __syncthreads();
            frag8 af[NI], bf[NJ];
#pragma unroll
            for (int i = 0; i < NI; ++i)
                af[i] = *(const frag8*)&As[(wm + i * 16 + lrow) * LDT + quad * 8];
#pragma unroll
            for (int j = 0; j < NJ; ++j)
                bf[j] = *(const frag8*)&Ws[(wn + j * 16 + lrow) * LDT + quad * 8];
#pragma unroll
            for (int i = 0; i < NI; ++i)
#pragma unroll
                for (int j = 0; j < NJ; ++j)
                    acc[i][j] = __builtin_amdgcn_mfma_f32_16x16x32_bf16(af[i], bf[j], acc[i][j], 0, 0, 0);
            __syncthreads();
        }
#pragma unroll
        for (int j = 0; j < NJ; ++j) {
            const int col = wn + j * 16 + lrow;
            float bv = bli[col];
#pragma unroll
            for (int i = 0; i < NI; ++i) {
                const int rowl = wm + i * 16 + quad * 4;
#pragma unroll
                for (int r = 0; r < 4; ++r) {
                    unsigned short h = f2b(lrelu01(acc[i][j][r] + bv));
                    NF[(size_t)(bn0 + rowl + r) * ldnf + col] = h;
                    SA[(rowl + r) * LDT2 + col] = h;
                }
            }
        }
        __syncthreads();
    }
    // ---- stage 2: q = (nf x Wgc^T) * dinv -> Q ----
    {
        f32x4 acc[NI][NJ] = {};
        for (int k0 = 0; k0 < BN; k0 += 32) {
#pragma unroll
            for (int h = 0; h < BN / 64; ++h) {
                int ch = tid + h * 256;
                int row = ch >> 2, cp = ch & 3;
                *(float4*)&Ws[row * LDT + cp * 8] =
                    *(const float4*)(Wgc + (size_t)row * BN + k0 + cp * 8);
            }
            __syncthreads();
            frag8 af[NI], bf[NJ];
#pragma unroll
            for (int i = 0; i < NI; ++i)
                af[i] = *(const frag8*)&SA[(wm + i * 16 + lrow) * LDT2 + k0 + quad * 8];
#pragma unroll
            for (int j = 0; j < NJ; ++j)
                bf[j] = *(const frag8*)&Ws[(wn + j * 16 + lrow) * LDT + quad * 8];
#pragma unroll
            for (int i = 0; i < NI; ++i)
#pragma unroll
                for (int j = 0; j < NJ; ++j)
                    acc[i][j] = __builtin_amdgcn_mfma_f32_16x16x32_bf16(af[i], bf[j], acc[i][j], 0, 0, 0);
            __syncthreads();
        }
#pragma unroll
        for (int j = 0; j < NJ; ++j) {
            const int col = wn + j * 16 + lrow;
#pragma unroll
            for (int i = 0; i < NI; ++i) {
                const int rowb = bn0 + wm + i * 16 + quad * 4;
#pragma unroll
                for (int r = 0; r < 4; ++r) {
                    float t = acc[i][j][r] * dinv[rowb + r];
                    Q[(size_t)(rowb + r) * ldq + col] = f2b(t);
                }
            }
        }
    }
}

// ---------------- fused conv2 + li2 + gc2 (block 2): 3-stage GEMM chain ----------------
// hmid = lrelu(A x Wcv^T + bcv) lives only in LDS; nf overwrites it in-place.
// A (hln1) and NF share the same buffer: each block fully consumes its global A
// rows in stage 0 before overwriting them (stage 1), and touches only own rows.
__launch_bounds__(256)
__global__ void k_cligc(const unsigned short* __restrict__ A,   // [n,128] hln1
                        const unsigned short* __restrict__ Wcv, const float* __restrict__ bcv,
                        const unsigned short* __restrict__ Wli, const float* __restrict__ bli,
                        const unsigned short* __restrict__ Wgc, const float* __restrict__ dinv,
                        unsigned short* __restrict__ NF,        // [n,128] (may alias A)
                        unsigned short* __restrict__ Q) {       // [n,128]
    constexpr int LDT = 40;
    constexpr int LDT2 = 136;
    __shared__ unsigned short As[128 * LDT];
    __shared__ unsigned short Ws[128 * LDT];
    __shared__ unsigned short SA[128 * LDT2];

    const int tid = threadIdx.x;
    const int wid = tid >> 6, lane = tid & 63;
    const int quad = lane >> 4, lrow = lane & 15;
    const int bn0 = blockIdx.x * 128;
    const int wm = (wid & 1) * 64;
    const int wn = (wid >> 1) * 64;

    // ---- stage 0: hmid = lrelu(A x Wcv^T + bcv) -> SA ----
    {
        f32x4 acc[4][4] = {};
        for (int k0 = 0; k0 < 128; k0 += 32) {
#pragma unroll
            for (int h = 0; h < 2; ++h) {
                int ch = tid + h * 256;
                int row = ch >> 2, cp = ch & 3;
                *(float4*)&As[row * LDT + cp * 8] =
                    *(const float4*)(A + (size_t)(bn0 + row) * 128 + k0 + cp * 8);
                *(float4*)&Ws[row * LDT + cp * 8] =
                    *(const float4*)(Wcv + (size_t)row * 128 + k0 + cp * 8);
            }
            __syncthreads();
            frag8 af[4], bf[4];
#pragma unroll
            for (int i = 0; i < 4; ++i)
                af[i] = *(const frag8*)&As[(wm + i * 16 + lrow) * LDT + quad * 8];
#pragma unroll
            for (int j = 0; j < 4; ++j)
                bf[j] = *(const frag8*)&Ws[(wn + j * 16 + lrow) * LDT + quad * 8];
#pragma unroll
            for (int i = 0; i < 4; ++i)
#pragma unroll
                for (int j = 0; j < 4; ++j)
                    acc[i][j] = __builtin_amdgcn_mfma_f32_16x16x32_bf16(af[i], bf[j], acc[i][j], 0, 0, 0);
            __syncthreads();
        }
#pragma unroll
        for (int j = 0; j < 4; ++j) {
            const int col = wn + j * 16 + lrow;
            float bv = bcv[col];
#pragma unroll
            for (int i = 0; i < 4; ++i) {
                const int rowl = wm + i * 16 + quad * 4;
#pragma unroll
                for (int r = 0; r < 4; ++r)
                    SA[(rowl + r) * LDT2 + col] = f2b(lrelu01(acc[i][j][r] + bv));
            }
        }
        __syncthreads();
    }
    // ---- stage 1: nf = lrelu(hmid x Wli^T + bli) -> NF global + SA (overwrite) ----
    {
        f32x4 acc[4][4] = {};
        for (int k0 = 0; k0 < 128; k0 += 32) {
#pragma unroll
            for (int h = 0; h < 2; ++h) {
                int ch = tid + h * 256;
                int row = ch >> 2, cp = ch & 3;
                *(float4*)&Ws[row * LDT + cp * 8] =
                    *(const float4*)(Wli + (size_t)row * 128 + k0 + cp * 8);
            }
            __syncthreads();
            frag8 af[4], bf[4];
#pragma unroll
            for (int i = 0; i < 4; ++i)
                af[i] = *(const frag8*)&SA[(wm + i * 16 + lrow) * LDT2 + k0 + quad * 8];
#pragma unroll
            for (int j = 0; j < 4; ++j)
                bf[j] = *(const frag8*)&Ws[(wn + j * 16 + lrow) * LDT + quad * 8];
#pragma unroll
            for (int i = 0; i < 4; ++i)
#pragma unroll
                for (int j = 0; j < 4; ++j)
                    acc[i][j] = __builtin_amdgcn_mfma_f32_16x16x32_bf16(af[i], bf[j], acc[i][j], 0, 0, 0);
            __syncthreads();
        }
#pragma unroll
        for (int j = 0; j < 4; ++j) {
            const int col = wn + j * 16 + lrow;
            float bv = bli[col];
#pragma unroll
            for (int i = 0; i < 4; ++i) {
                const int rowl = wm + i * 16 + quad * 4;
#pragma unroll
                for (int r = 0; r < 4; ++r) {
                    unsigned short h = f2b(lrelu01(acc[i][j][r] + bv));
                    NF[(size_t)(bn0 + rowl + r) * 128 + col] = h;
                    SA[(rowl + r) * LDT2 + col] = h;
                }
            }
        }
        __syncthreads();
    }
    // ---- stage 2: q = (nf x Wgc^T) * dinv -> Q ----
    {
        f32x4 acc[4][4] = {};
        for (int k0 = 0; k0 < 128; k0 += 32) {
#pragma unroll
            for (int h = 0; h < 2; ++h) {
                int ch = tid + h * 256;
                int row = ch >> 2, cp = ch & 3;
                *(float4*)&Ws[row * LDT + cp * 8] =
                    *(const float4*)(Wgc + (size_t)row * 128 + k0 + cp * 8);
            }
            __syncthreads();
            frag8 af[4], bf[4];
#pragma unroll
            for (int i = 0; i < 4; ++i)
                af[i] = *(const frag8*)&SA[(wm + i * 16 + lrow) * LDT2 + k0 + quad * 8];
#pragma unroll
            for (int j = 0; j < 4; ++j)
                bf[j] = *(const frag8*)&Ws[(wn + j * 16 + lrow) * LDT + quad * 8];
#pragma unroll
            for (int i = 0; i < 4; ++i)
#pragma unroll
                for (int j = 0; j < 4; ++j)
                    acc[i][j] = __builtin_amdgcn_mfma_f32_16x16x32_bf16(af[i], bf[j], acc[i][j], 0, 0, 0);
            __syncthreads();
        }
#pragma unroll
        for (int j = 0; j < 4; ++j) {
            const int col = wn + j * 16 + lrow;
#pragma unroll
            for (int i = 0; i < 4; ++i) {
                const int rowb = bn0 + wm + i * 16 + quad * 4;
#pragma unroll
                for (int r = 0; r < 4; ++r)
                    Q[(size_t)(rowb + r) * 128 + col] = f2b(acc[i][j][r] * dinv[rowb + r]);
            }
        }
    }
}

// out = c4 (from pooled) + xdot  — tiny
__global__ void k_out2(const float* __restrict__ xdot, const float* __restrict__ ow,
                       const float* __restrict__ ob, const float* __restrict__ pooled,
                       float* __restrict__ out, int n, float invn) {
    __shared__ float c4s[4];
    int tid = threadIdx.x;
    {
        int j = tid >> 6, lane = tid & 63;
        float s = 0.f;
        for (int c = lane; c < 256; c += 64) s += pooled[c] * invn * ow[j * 320 + c];
#pragma unroll
        for (int off = 32; off > 0; off >>= 1) s += __shfl_down(s, off);
        if (lane == 0) c4s[j] = s + ob[j];
    }
    __syncthreads();
    int node = blockIdx.x * 256 + tid;
    if (node >= n) return;
    float4 xd = *(const float4*)(xdot + (size_t)node * 4);
    *(float4*)(out + (size_t)node * 4) =
        make_float4(c4s[0] + xd.x, c4s[1] + xd.y, c4s[2] + xd.z, c4s[3] + xd.w);
}

// ================= launch =================
// Buffer lifetimes:
//   F1 [N,128]f32: z2 only
//   B1 [N,64] u16: h1 -> nf1
//   B2 [(N*128+128)]u16: A3F -> q1 (first N*64) -> q2.  The 128-entry row at
//       offset N*128 is zeroed in the prologue and never overwritten: shared
//       gather dummy row (idx 2N for CH=64 rows, idx N for CH=128 rows).
//   B3 [N,128]u16: hln1 -> nf2 (k_cligc rewrites its own rows in place)
//   H  [N,320]u16: xg cols 256.. (early), LN2 out cols 0..255 (late)
//   XD [N,4]f32:   per-node xg(dot)ow partial for the head

extern "C" void kernel_launch(void* const* d_in, const int* in_sizes, int n_in,
                              void* d_out, int out_size, void* d_ws, size_t ws_size,
                              hipStream_t stream) {
    const float* x   = (const float*)d_in[0];
    const int*   ei  = (const int*)d_in[1];
    const float* c1w = (const float*)d_in[2];  const float* c1b = (const float*)d_in[3];
    const float* c2w = (const float*)d_in[4];  const float* c2b = (const float*)d_in[5];
    const float* c3w = (const float*)d_in[6];  const float* c3b = (const float*)d_in[7];
    const float* f1w = (const float*)d_in[8];  const float* f1b = (const float*)d_in[9];
    const float* f2w = (const float*)d_in[10]; const float* f2bp = (const float*)d_in[11];
    const float* f3w = (const float*)d_in[12]; const float* f3b = (const float*)d_in[13];
    const float* cv1w = (const float*)d_in[14]; const float* cv1b = (const float*)d_in[15];
    const float* li1w = (const float*)d_in[16]; const float* li1b = (const float*)d_in[17];
    const float* gc1w = (const float*)d_in[18]; const float* gc1b = (const float*)d_in[19];
    const float* ln1g = (const float*)d_in[20]; const float* ln1b = (const float*)d_in[21];
    const float* cv2w = (const float*)d_in[22]; const float* cv2b = (const float*)d_in[23];
    const float* li2w = (const float*)d_in[24]; const float* li2b = (const float*)d_in[25];
    const float* gc2w = (const float*)d_in[26]; const float* gc2b = (const float*)d_in[27];
    const float* ln2g = (const float*)d_in[28]; const float* ln2b = (const float*)d_in[29];
    const float* cv3w = (const float*)d_in[30]; const float* cv3b = (const float*)d_in[31];
    const float* ow  = (const float*)d_in[32]; const float* ob  = (const float*)d_in[33];
    float* out = (float*)d_out;

    const int N = in_sizes[0] / 3;
    const int E = in_sizes[1] / 2;
    const int* srcI = ei;
    const int* dstI = ei + E;

    char* base = (char*)d_ws;
    size_t off = 0;
    auto take = [&](size_t bytes) -> char* {
        char* p = base + off;
        off = (off + bytes + 255) & ~(size_t)255;
        return p;
    };
    int*   deg    = (int*)  take((size_t)N * 4);
    float* sm     = (float*)take(8192 * 4);      // adjacent to deg -> single memset
    float* dinv   = (float*)take((size_t)N * 4);
    int*   startv = (int*)  take((size_t)N * 4);
    int*   rank   = (int*)  take((size_t)E * 4);
    int*   csr    = (int*)  take((size_t)E * 4);
    int*   bsum   = (int*)  take(512 * 4);
    unsigned short* WB = (unsigned short*)take(278528 * 2);
    unsigned short* H  = (unsigned short*)take((size_t)N * 320 * 2);
    float* F1 = (float*)take((size_t)N * 128 * 4);
    unsigned short* B1 = (unsigned short*)take((size_t)N * 64 * 2);
    unsigned short* B2 = (unsigned short*)take(((size_t)N * 128 + 128) * 2);
    unsigned short* B3 = (unsigned short*)take((size_t)N * 128 * 2);
    float* XD = (float*)take((size_t)N * 4 * 4);

    unsigned short* c2wb  = WB + 0;
    unsigned short* c3wf  = WB + 8192;   // fragment-order c3 weights (8 x 16384)
    unsigned short* li1wb = WB + 139264;
    unsigned short* gc1wb = WB + 143360;
    unsigned short* cv2wb = WB + 147456;
    unsigned short* li2wb = WB + 163840;
    unsigned short* gc2wb = WB + 180224;
    unsigned short* cv3wb = WB + 196608;

    float* sum2 = sm + 0;    float* ss2 = sm + 128;
    float* sum3 = sm + 256;  float* ss3 = sm + 1280;
    unsigned* maxk = (unsigned*)(sm + 2304);
    float* pooled = sm + 3328;
    unsigned* dmax = (unsigned*)(sm + 3584);   // 3584..3711
    unsigned* cnt1 = (unsigned*)(sm + 3712);
    unsigned* cnt2 = (unsigned*)(sm + 3713);
    float* T9  = sm + 3968;
    float* a1  = sm + 5120;   // 512 floats
    float* a2  = sm + 5760;   // 256 floats

    const float invn = 1.0f / (float)N;
    const dim3 blk(256);
    const unsigned GX = (unsigned)(N / 128);
    const unsigned NB = cdivu((unsigned)N, 256);
    const unsigned EB = cdivu((unsigned)E, 256);
    const unsigned WCB = cdivu(278528u, 256);
    const unsigned PB = cdivu((unsigned)N * 16, 256);
    const unsigned NZ = 8 * GX;

    // merged memset: deg (padded to 256B) + sm prefix (stats + spin counters)
    size_t degpad = ((size_t)N * 4 + 255) & ~(size_t)255;
    hipMemsetAsync(deg, 0, degpad + 3720 * 4, stream);
    // shared 256B zero row at B2 + N*128 entries (gather dummy for both glns)
    hipMemsetAsync(B2 + (size_t)N * 128, 0, 256, stream);

    // FK1: degree/rank atomics || weight pack || tnet-c1
    FK1<<<EB + WCB + NB, blk, 0, stream>>>(dstI, deg, rank, E, (int)EB,
                                           c2w, c3w, li1w, gc1w, cv2w, li2w, gc2w, cv3w,
                                           WB, (int)WCB, x, c1w, c1b, B1, N);
    // FK2: z2 GEMM (stats) || local scan + dinv
    FK2<<<GX + NB, blk, 0, stream>>>(B1, 64, 64, c2wb, c2b, F1, 128,
                                     sum2, ss2, dmax, (int)GX, deg, startv, bsum, dinv, N);
    // FK3: pre-BN repack || block-sum scan
    FK3<<<PB + 1, blk, 0, stream>>>(F1, sum2, ss2, B2, N * 16, invn, (int)PB, bsum, (int)NB);
    // FK4: z3 stats GEMM then CSR fill (appended, phase-serialized in-kernel)
    FK4<<<NZ + EB, blk, 0, stream>>>(B2, c3wf, c3b, sum3, ss3, maxk, (int)NZ, (int)GX,
                                     srcI, dstI, rank, startv, bsum, csr, E);
    // TNet tail: fc1+fc2+fc3 fused via 32-block spin barriers
    k_tnet<<<32, blk, 0, stream>>>(sum3, ss3, maxk, f1w, f1b, f2w, f2bp, f3w, f3b,
                                   a1, a2, T9, cnt1, cnt2, invn);
    // xg + xdot
    k_xg2<<<NB, blk, 0, stream>>>(x, T9, cv1w, cv1b, ow, H + 256, XD, N);

    // ---- GCN block 1 (C=64) ----
    k_ligc<64><<<GX, blk, 0, stream>>>(H + 256, 320, 64, li1wb, li1b, gc1wb, dinv, B1, 64, B2, 64);
    k_gln<64><<<cdivu((unsigned)N, 4), blk, 0, stream>>>(
        startv, bsum, deg, csr, B2, B1, dinv, gc1b, ln1g, ln1b, B3, 128, N, 2 * N);

    // ---- GCN block 2 (C=128): conv2+li2+gc2 fused ----
    k_cligc<<<GX, blk, 0, stream>>>(B3, cv2wb, cv2b, li2wb, li2b, gc2wb, dinv, B3, B2);
    k_gln<128><<<cdivu((unsigned)N, 4), blk, 0, stream>>>(
        startv, bsum, deg, csr, B2, B3, dinv, gc2b, ln2g, ln2b, H, 320, N, N);

    // ---- conv3 (K=320 -> 256), SWAP grid so both col-blocks of a row-tile are adjacent ----
    k_mgemm<128, (MF_BIAS | MF_LRELU | MF_COLSUM), 1><<<dim3(2, GX), blk, 0, stream>>>(
        H, 320, 320, cv3wb, cv3b, nullptr, nullptr, 0, nullptr, pooled, nullptr, nullptr);

    // ---- head ----
    k_out2<<<NB, blk, 0, stream>>>(XD, ow, ob, pooled, out, N, invn);
}